// Round 11
// baseline (1041.378 us; speedup 1.0000x reference)
//
#include <hip/hip_runtime.h>
#include <math.h>

#define NN 16384      // nodes
#define E1N 65536     // edges level 1
#define NBATCH 256
#define NC2 65536     // clusters (level 2 and level 3)
#define A2N 131072
#define A3N 196608
#define ELV 262144    // edges per level graph
#define KH 128        // edge-MLP hidden
#define OCS 136       // oc stride (f16)
#define MNSTR 1092    // M node stride (f16) — R8-verified low-conflict
#define ECAP 96       // edges per super-tile

typedef _Float16 f16;
typedef _Float16 f16x2 __attribute__((ext_vector_type(2)));
typedef _Float16 f16x4 __attribute__((ext_vector_type(4)));
typedef _Float16 f16x8 __attribute__((ext_vector_type(8)));
typedef float    f32x4 __attribute__((ext_vector_type(4)));

__device__ __forceinline__ float elu1(float x){ return x > 0.f ? x : expm1f(x); }

__device__ __forceinline__ float dot2acc(f16x2 a, f16x2 b, float c){
#if __has_builtin(__builtin_amdgcn_fdot2)
  return __builtin_amdgcn_fdot2(a, b, c, false);
#else
  return fmaf((float)a[0], (float)b[0], fmaf((float)a[1], (float)b[1], c));
#endif
}

// ---------------- segmented 3-phase scan ----------------
__global__ __launch_bounds__(256) void k_scan1(const int* __restrict__ deg,
    int* __restrict__ ptr, int* __restrict__ partials){
  __shared__ int buf[256];
  int i = blockIdx.x*256 + threadIdx.x, t = threadIdx.x;
  int v = deg[i];
  buf[t] = v; __syncthreads();
  for (int o = 1; o < 256; o <<= 1){
    int x = (t >= o) ? buf[t-o] : 0;
    __syncthreads(); buf[t] += x; __syncthreads();
  }
  ptr[i] = buf[t] - v;
  if (t == 255) partials[blockIdx.x] = buf[255];
}

__global__ __launch_bounds__(256) void k_scan2seg(int* __restrict__ partials, int nb){
  __shared__ int buf[256];
  int t = threadIdx.x, base = blockIdx.x*nb;
  int v = (t < nb) ? partials[base + t] : 0;
  buf[t] = v; __syncthreads();
  for (int o = 1; o < 256; o <<= 1){
    int x = (t >= o) ? buf[t-o] : 0;
    __syncthreads(); buf[t] += x; __syncthreads();
  }
  if (t < nb) partials[base + t] = buf[t] - v;
}

__global__ __launch_bounds__(256) void k_scan3(const int* __restrict__ partials,
    int* __restrict__ ptr, int* __restrict__ cur){
  int i = blockIdx.x*256 + threadIdx.x;
  int v = ptr[i] + partials[blockIdx.x];
  ptr[i] = v; cur[i] = v;
}

// ---------------- level-1 CSR (src + dst in one pass) ----------------
__global__ __launch_bounds__(256) void k_count_edge_dual(const int* __restrict__ ei, int* __restrict__ deg){
  int e = blockIdx.x*256 + threadIdx.x;
  if (e >= E1N) return;
  atomicAdd(&deg[ei[e]], 1);
  atomicAdd(&deg[NN + ei[E1N + e]], 1);
}

__global__ __launch_bounds__(256) void k_fill_edge_dual(const int* __restrict__ ei, int* __restrict__ cur,
    int* __restrict__ eids, int* __restrict__ srcs, int* __restrict__ dpos){
  int e = blockIdx.x*256 + threadIdx.x;
  if (e >= E1N) return;
  int s = ei[e], d = ei[E1N + e];
  int p = atomicAdd(&cur[s], 1);
  eids[p] = e; srcs[p] = s;
  int p2 = atomicAdd(&cur[NN + d], 1);
  dpos[p2] = p;
}

// ---------------- level-2/3 CSR (dual) ----------------
__global__ __launch_bounds__(256) void k_count_assign_dual(const int* __restrict__ a2c,
    const int* __restrict__ a3c, int* __restrict__ ldegA){
  int i = blockIdx.x*256 + threadIdx.x;
  if (i < A2N) atomicAdd(&ldegA[a2c[i]], 1);
  else if (i < A2N + A3N) atomicAdd(&ldegA[NC2 + a3c[i - A2N]], 1);
}

__global__ __launch_bounds__(256) void k_fill_assign_dual(const int* __restrict__ a2n,
    const int* __restrict__ a2c, const int* __restrict__ a3n, const int* __restrict__ a3c,
    int* __restrict__ curA, int* __restrict__ ans2, int* __restrict__ ans3){
  int i = blockIdx.x*256 + threadIdx.x;
  if (i < A2N){
    int p = atomicAdd(&curA[a2c[i]], 1); ans2[p] = a2n[i];
  } else if (i < A2N + A3N){
    int j = i - A2N;
    int p = atomicAdd(&curA[NC2 + a3c[j]], 1); ans3[p] = a3n[j];
  }
}

__global__ __launch_bounds__(256) void k_count_dst_dual(const int* __restrict__ ei2,
    const int* __restrict__ ei3, int* __restrict__ ldegD){
  int i = blockIdx.x*256 + threadIdx.x;
  if (i < ELV) atomicAdd(&ldegD[ei2[ELV + i]], 1);
  else if (i < 2*ELV) atomicAdd(&ldegD[NC2 + ei3[ELV + (i - ELV)]], 1);
}

__global__ __launch_bounds__(256) void k_fill_dst_dual(const int* __restrict__ ei2,
    const int* __restrict__ ei3, int* __restrict__ curD,
    int* __restrict__ dsrc2, int* __restrict__ dsrc3){
  int i = blockIdx.x*256 + threadIdx.x;
  if (i < ELV){
    int p = atomicAdd(&curD[ei2[ELV + i]], 1); dsrc2[p] = ei2[i];
  } else if (i < 2*ELV){
    int j = i - ELV;
    int p = atomicAdd(&curD[NC2 + ei3[ELV + j]], 1); dsrc3[p] = ei3[j];
  }
}

// ---------------- small converts ----------------
__global__ __launch_bounds__(256) void k_cvt16(const float* __restrict__ v, f16* __restrict__ o, int n){
  int t = blockIdx.x*256 + threadIdx.x;
  if (t < n) o[t] = (f16)v[t];
}

// ---------------- NNConv pieces ----------------
__global__ __launch_bounds__(256) void k_packPrep(const float* __restrict__ root,
    const float* __restrict__ b2, f16* __restrict__ Bp, int mi, int mo, int S, int NB){
  int t = blockIdx.x*256 + threadIdx.x;
  if (t >= NB*S*512) return;
  int j = t & 7, l = (t >> 3) & 63, cs = t >> 9;
  int s = cs % S, c = cs / S;
  int k_in = s*32 + ((l>>4)<<3) + j;
  int n = c*16 + (l & 15);
  float v = 0.f;
  if (k_in < mi) v = (n < mo) ? root[k_in*mo + n] : b2[k_in*mo + (n - mo)];
  Bp[t] = (f16)v;
}

// prep[n,o] = bias[o] + (x@root)[n,o]; bterm[n,o] = (x@b2)[n,o]
template<int MI, int S, int NB, int MO>
__global__ __launch_bounds__(256) void k_prep_mfma(const f16* __restrict__ A,
    const f16* __restrict__ Bp, const float* __restrict__ bias,
    float* __restrict__ prep, float* __restrict__ bterm){
  int l = threadIdx.x & 63, w = threadIdx.x >> 6;
  int r0 = blockIdx.x*64 + w*16;
  const f16* arow = A + (size_t)(r0 + (l & 15))*MI;
  f16x8 a[S];
  #pragma unroll
  for (int s=0;s<S;s++){
    int koff = s*32 + ((l>>4)<<3);
    if (koff < MI) a[s] = *(const f16x8*)(arow + koff);
    else           a[s] = (f16x8){0,0,0,0,0,0,0,0};
  }
  #pragma unroll
  for (int c=0;c<NB;c++){
    f32x4 acc = (f32x4){0.f,0.f,0.f,0.f};
    #pragma unroll
    for (int s=0;s<S;s++){
      f16x8 b = *(const f16x8*)(Bp + ((size_t)(c*S + s)*64 + l)*8);
      acc = __builtin_amdgcn_mfma_f32_16x16x32_f16(a[s], b, acc, 0, 0, 0);
    }
    int col = c*16 + (l & 15);
    #pragma unroll
    for (int r=0;r<4;r++){
      int row = r0 + ((l>>4)<<2) + r;
      if (col < MO) prep[(size_t)row*MO + col] = acc[r] + bias[col];
      else          bterm[(size_t)row*MO + (col - MO)] = acc[r];
    }
  }
}

__global__ __launch_bounds__(256) void k_w2pack_full(const float* __restrict__ W2,
    f16* __restrict__ Bp, int mi, int mo, int S){
  int t = blockIdx.x*256 + threadIdx.x;
  if (t >= mo*8*S*512) return;
  int j = t & 7, l = (t >> 3) & 63, cs = t >> 9;
  int s = cs % S, q = cs / S;
  int oc = q >> 3;
  int k  = (q & 7)*16 + (l & 15);
  int i  = s*32 + ((l>>4)<<3) + j;
  float v = (i < mi) ? W2[(size_t)k*mi*mo + (size_t)i*mo + oc] : 0.f;
  Bp[t] = (f16)v;
}

// FUSED NNConv v6: 16 nodes/block, 8-oc chunks. Stage 2 re-partitioned as
// (eslot, k-slice): h held in REGISTERS (edge-MLP computed per-thread, no hb
// LDS buffer), M read as broadcast-friendly slices, butterfly reduce over the
// kg octet, lane kg==0 stores the packed 8-oc f16x8. LDS 42 KB -> 3 blocks/CU.
template<int MI, int S, int MO>
__global__ __launch_bounds__(256,3) void k_nnconv_fused6(const f16* __restrict__ xin16,
    const f16* __restrict__ W2p,
    const int* __restrict__ rowptr, const int* __restrict__ rowend,
    const int* __restrict__ srcs, const int* __restrict__ eids,
    const float* __restrict__ ea, const float* __restrict__ W1,
    const float* __restrict__ b1,
    const float* __restrict__ bterm, f16* __restrict__ msg16){
  __shared__ __align__(16) f16   M[16*MNSTR];    // 34944 B
  __shared__ __align__(16) float eas[ECAP*8];    //  3072 B
  __shared__ float bt[16*MO];                    // 4096/2048 B
  int t = threadIdx.x, l = t & 63, w = t >> 6;
  int n0 = blockIdx.x*16;
  int estart = rowptr[n0], eend = rowend[n0+15];
  if (estart >= eend) return;                    // block-uniform
  for (int idx = t; idx < 16*MO; idx += 256) bt[idx] = bterm[(size_t)n0*MO + idx];
  const f16* arow = xin16 + (size_t)(n0 + (l&15))*MI;
  f16x8 a[S];
  #pragma unroll
  for (int s=0;s<S;s++){
    int koff = s*32 + ((l>>4)<<3);
    if (koff < MI) a[s] = *(const f16x8*)(arow + koff);
    else           a[s] = (f16x8){0,0,0,0,0,0,0,0};
  }
  const int NCHUNK = MO/8;
  const int NR = ECAP/32;
  int eslot = t >> 3, kg = t & 7;                // 32 edge slots x 8 k-slices
  for (int ebase = estart; ebase < eend; ebase += ECAP){
    int ecnt = eend - ebase; if (ecnt > ECAP) ecnt = ECAP;
    // ---- stage ea rows ----
    for (int idx = t; idx < ecnt*8; idx += 256){
      int e_ = idx >> 3, i = idx & 7;
      eas[idx] = (i < 7) ? ea[(size_t)eids[ebase + e_]*7 + i] : 0.f;
    }
    __syncthreads();
    // ---- per-thread edge-MLP into registers: h[e, kg*16 .. +16) for <=3 edges ----
    f16x8 hreg[NR][2];
    int   sreg[NR];
    #pragma unroll
    for (int r2 = 0; r2 < NR; r2++){
      int ee = r2*32 + eslot;
      if (ee < ecnt){
        sreg[r2] = srcs[ebase + ee];
        const float* xr = &eas[ee*8];
        float xv[7];
        #pragma unroll
        for (int i=0;i<7;i++) xv[i] = xr[i];
        float hacc[16];
        #pragma unroll
        for (int j4=0;j4<4;j4++){
          int k0 = kg*16 + j4*4;
          float4 acc4 = *(const float4*)(b1 + k0);
          #pragma unroll
          for (int i=0;i<7;i++){
            float4 wv = *(const float4*)(W1 + i*KH + k0);
            acc4.x = fmaf(xv[i], wv.x, acc4.x);
            acc4.y = fmaf(xv[i], wv.y, acc4.y);
            acc4.z = fmaf(xv[i], wv.z, acc4.z);
            acc4.w = fmaf(xv[i], wv.w, acc4.w);
          }
          hacc[j4*4+0] = fmaxf(acc4.x, 0.f);
          hacc[j4*4+1] = fmaxf(acc4.y, 0.f);
          hacc[j4*4+2] = fmaxf(acc4.z, 0.f);
          hacc[j4*4+3] = fmaxf(acc4.w, 0.f);
        }
        #pragma unroll
        for (int j=0;j<8;j++){ hreg[r2][0][j] = (f16)hacc[j]; hreg[r2][1][j] = (f16)hacc[8+j]; }
      }
    }
    // ---- chunk loop ----
    for (int c = 0; c < NCHUNK; c++){
      // stage 1: MFMA M chunk -> LDS (unchanged from v5)
      #pragma unroll
      for (int tt = 0; tt < 16; tt++){
        int q = c*64 + w*16 + tt;
        f32x4 acc = (f32x4){0.f,0.f,0.f,0.f};
        #pragma unroll
        for (int s=0;s<S;s++){
          f16x8 b = *(const f16x8*)(W2p + ((size_t)(q*S + s)*64 + l)*8);
          acc = __builtin_amdgcn_mfma_f32_16x16x32_f16(a[s], b, acc, 0, 0, 0);
        }
        int ocl = w*2 + (tt>>3);
        int kpos = (tt&7)*16 + (l & 15);
        f16* mp = &M[ocl*OCS + kpos];
        #pragma unroll
        for (int r=0;r<4;r++)
          mp[(size_t)(((l>>4)<<2) + r)*MNSTR] = (f16)acc[r];
      }
      __syncthreads();
      // stage 2: (edge, k-slice) partials + butterfly over kg octet
      #pragma unroll
      for (int r2 = 0; r2 < NR; r2++){
        int ee = r2*32 + eslot;
        if (ee < ecnt){
          int e = ebase + ee;
          int ln = sreg[r2] - n0;
          const f16* mrow = &M[(size_t)ln*MNSTR + kg*16];
          f16x8 h0 = hreg[r2][0], h1 = hreg[r2][1];
          float p[8];
          #pragma unroll
          for (int oc=0;oc<8;oc++){
            f16x8 m0 = *(const f16x8*)(mrow + oc*OCS);
            f16x8 m1 = *(const f16x8*)(mrow + oc*OCS + 8);
            float acc = 0.f;
            #pragma unroll
            for (int j=0;j<4;j++){
              acc = dot2acc((f16x2){h0[2*j],h0[2*j+1]}, (f16x2){m0[2*j],m0[2*j+1]}, acc);
              acc = dot2acc((f16x2){h1[2*j],h1[2*j+1]}, (f16x2){m1[2*j],m1[2*j+1]}, acc);
            }
            p[oc] = acc;
          }
          #pragma unroll
          for (int m = 1; m < 8; m <<= 1){
            #pragma unroll
            for (int oc=0;oc<8;oc++) p[oc] += __shfl_xor(p[oc], m, 64);
          }
          if (kg == 0){
            f16x8 out;
            #pragma unroll
            for (int oc=0;oc<8;oc++) out[oc] = (f16)(p[oc] + bt[ln*MO + c*8 + oc]);
            *(f16x8*)&msg16[(size_t)e*MO + c*8] = out;
          }
        }
      }
      __syncthreads();
    }
  }
}

// dst-CSR gather of conv messages: out16[n,o] = elu(prep[n,o] + sum msg[dpos[p], o])
template<int MO>
__global__ __launch_bounds__(256) void k_msg_gather(const int* __restrict__ dptr,
    const int* __restrict__ dend, const int* __restrict__ dpos,
    const f16* __restrict__ msg, const float* __restrict__ prep,
    f16* __restrict__ out16){
  int t = threadIdx.x, l = t & 63, w = t >> 6;
  int n, o;
  if (MO == 64){ n = blockIdx.x*4 + w; o = l; }
  else         { n = blockIdx.x*8 + w*2 + (l>>5); o = l & 31; }
  int st = dptr[n], en = dend[n];
  float acc = prep[(size_t)n*MO + o];
  int p = st;
  for (; p+1 < en; p += 2){
    int q0 = dpos[p], q1 = dpos[p+1];
    acc += (float)msg[(size_t)q0*MO + o];
    acc += (float)msg[(size_t)q1*MO + o];
  }
  if (p < en) acc += (float)msg[(size_t)dpos[p]*MO + o];
  out16[(size_t)n*MO + o] = (f16)elu1(acc);
}

// ---------------- pooling via cluster-CSR, dual-level ----------------
__global__ __launch_bounds__(256) void k_pool_gather_dual(const int* __restrict__ aptr,
    const int* __restrict__ aend, const int* __restrict__ ans2, const int* __restrict__ ans3,
    const f16* __restrict__ h, const float* __restrict__ iso2, const float* __restrict__ iso3,
    f16* __restrict__ h16){
  int l = threadIdx.x & 63, w = threadIdx.x >> 6;
  int cg = blockIdx.x*4 + w;               // [0, 2*NC2)
  int lvl = cg >= NC2;
  int c = cg - lvl*NC2;
  const int* ans = lvl ? ans3 : ans2;
  const float* iso = lvl ? iso3 : iso2;
  int st = aptr[cg], en = aend[cg];
  float acc = 0.f;
  int e = st;
  for (; e+1 < en; e += 2){
    int n0 = ans[e], n1 = ans[e+1];
    acc += (float)h[(size_t)n0*64 + l];
    acc += (float)h[(size_t)n1*64 + l];
  }
  if (e < en) acc += (float)h[(size_t)ans[e]*64 + l];
  int cnt = en - st;
  float val = (cnt > 0) ? acc / (float)cnt : 0.f;
  h16[(size_t)cg*128 + l] = (f16)val;
  h16[(size_t)cg*128 + 64 + l] = (f16)iso[(size_t)c*64 + l];
}

// ---------------- GraphConv (dual-level) ----------------
#define BP_O4 0
#define BP_O5 16384
#define BP_O6 24576
#define BP_O7 40960
__global__ __launch_bounds__(256) void k_packB_all(
    const float* __restrict__ W4r, const float* __restrict__ W4o,
    const float* __restrict__ W5r, const float* __restrict__ W5o,
    const float* __restrict__ W6r, const float* __restrict__ W6o,
    const float* __restrict__ W7r, const float* __restrict__ W7o,
    f16* __restrict__ Bp){
  int t = blockIdx.x*256 + threadIdx.x;
  const float *Wrel, *Wroot; int S, base;
  if      (t < BP_O5){ Wrel=W4r; Wroot=W4o; S=4; base=BP_O4; }
  else if (t < BP_O6){ Wrel=W5r; Wroot=W5o; S=2; base=BP_O5; }
  else if (t < BP_O7){ Wrel=W6r; Wroot=W6o; S=4; base=BP_O6; }
  else if (t < 49152){ Wrel=W7r; Wroot=W7o; S=2; base=BP_O7; }
  else return;
  int u = t - base;
  int j = u & 7, l = (u >> 3) & 63, cs = u >> 9;
  int s = cs % S, c = cs / S;
  int k = s*32 + ((l>>4)<<3) + j;
  int n = (c<<4) + (l & 15);
  float v = (n < 64) ? Wrel[k*64 + n] : Wroot[k*64 + (n - 64)];
  Bp[t] = (f16)v;
}

template<int S>
__global__ __launch_bounds__(256) void k_gc_mfma_dual(const f16* __restrict__ Abase,
    const f16* __restrict__ Bp, int bpo2, int bpo3,
    const float* __restrict__ bias2, const float* __restrict__ bias3,
    f16* __restrict__ y16, f16* __restrict__ rbuf16){
  const int half = NC2/64;
  int lvl = blockIdx.x >= half;
  int bloc = blockIdx.x - lvl*half;
  const f16* A = Abase + (size_t)lvl*NC2*(S*32);
  const f16* B = Bp + (lvl ? bpo3 : bpo2);
  const float* bias = lvl ? bias3 : bias2;
  f16* y  = y16 + (size_t)lvl*NC2*64;
  f16* rb = rbuf16 + (size_t)lvl*NC2*64;
  int l = threadIdx.x & 63, w = threadIdx.x >> 6;
  int r0 = bloc*64 + w*16;
  const f16* arow = A + (size_t)(r0 + (l & 15))*(S*32);
  f16x8 a[S];
  #pragma unroll
  for (int s=0;s<S;s++) a[s] = *(const f16x8*)(arow + s*32 + ((l>>4)<<3));
  f32x4 acc[8];
  #pragma unroll
  for (int c=0;c<8;c++) acc[c] = (f32x4){0.f,0.f,0.f,0.f};
  #pragma unroll
  for (int c=0;c<8;c++){
    #pragma unroll
    for (int s=0;s<S;s++){
      f16x8 b = *(const f16x8*)(B + ((size_t)(c*S + s)*64 + l)*8);
      acc[c] = __builtin_amdgcn_mfma_f32_16x16x32_f16(a[s], b, acc[c], 0, 0, 0);
    }
  }
  #pragma unroll
  for (int c=0;c<8;c++){
    int col = c*16 + (l & 15);
    #pragma unroll
    for (int r=0;r<4;r++){
      int row = r0 + ((l>>4)<<2) + r;
      if (col < 64) y[(size_t)row*64 + col] = (f16)acc[c][r];
      else          rb[(size_t)row*64 + (col-64)] = (f16)(acc[c][r] + bias[col-64]);
    }
  }
}

__global__ __launch_bounds__(256) void k_gc_gather_dual(const int* __restrict__ dptrD,
    const int* __restrict__ dcurD, const int* __restrict__ dsrc2, const int* __restrict__ dsrc3,
    const f16* __restrict__ y16, const f16* __restrict__ rbuf16,
    f16* __restrict__ obase){
  int l = threadIdx.x & 63, w = threadIdx.x >> 6;
  int ng = blockIdx.x*4 + w;               // [0, 2*NC2)
  int lvl = ng >= NC2;
  int n = ng - lvl*NC2;
  const int* dsrc = lvl ? dsrc3 : dsrc2;
  const f16* y  = y16 + (size_t)lvl*NC2*64;
  const f16* rb = rbuf16 + (size_t)lvl*NC2*64;
  f16* o = obase + (size_t)lvl*NC2*64;
  int st = dptrD[ng], en = dcurD[ng];
  float acc = (float)rb[(size_t)n*64 + l];
  int e = st;
  for (; e+1 < en; e += 2){
    int s0 = dsrc[e], s1 = dsrc[e+1];
    acc += (float)y[(size_t)s0*64 + l];
    acc += (float)y[(size_t)s1*64 + l];
  }
  if (e < en) acc += (float)y[(size_t)dsrc[e]*64 + l];
  o[(size_t)n*64 + l] = (f16)elu1(acc);
}

// ---------------- 3-way sorted-segment batch sum ----------------
__device__ __forceinline__ int lowerb(const int* __restrict__ a, int n, int key){
  int lo = 0, hi = n;
  while (lo < hi){ int m = (lo + hi) >> 1; if (a[m] < key) lo = m + 1; else hi = m; }
  return lo;
}

__global__ __launch_bounds__(256) void k_batchsum3(const int* __restrict__ b1,
    const int* __restrict__ b2, const int* __restrict__ b3,
    const f16* __restrict__ s1, const f16* __restrict__ s2, const f16* __restrict__ s3,
    float* __restrict__ x123){
  __shared__ float red[4][64];
  int seg = blockIdx.x >> 8, b = blockIdx.x & 255;
  const int* batch = (seg==0) ? b1 : ((seg==1) ? b2 : b3);
  const f16* src   = (seg==0) ? s1 : ((seg==1) ? s2 : s3);
  int nn = (seg==0) ? NN : NC2;
  int lo = lowerb(batch, nn, b);
  int hi = lowerb(batch, nn, b+1);
  int col = threadIdx.x & 63, wq = threadIdx.x >> 6;
  float acc = 0.f;
  for (int n = lo + wq; n < hi; n += 4) acc += (float)src[(size_t)n*64 + col];
  red[wq][col] = acc;
  __syncthreads();
  if (threadIdx.x < 64){
    float s = red[0][threadIdx.x] + red[1][threadIdx.x] + red[2][threadIdx.x] + red[3][threadIdx.x];
    x123[b*192 + seg*64 + threadIdx.x] = s;
  }
}

// ---------------- FC head ----------------
__global__ __launch_bounds__(256) void k_fc1(const float* __restrict__ x123,
    const float* __restrict__ W, const float* __restrict__ b, float* __restrict__ t1){
  int t = blockIdx.x*256 + threadIdx.x;
  if (t >= NBATCH*64) return;
  int bb = t >> 6, o = t & 63;
  const float* xr = x123 + bb*192;
  float acc = b[o];
  for (int j=0;j<192;j++) acc = fmaf(xr[j], W[j*64+o] + W[(192+j)*64+o], acc);
  t1[t] = elu1(acc);
}

__global__ __launch_bounds__(256) void k_fc2(const float* __restrict__ t1,
    const float* __restrict__ W, const float* __restrict__ b, float* __restrict__ t2){
  int t = blockIdx.x*256 + threadIdx.x;
  if (t >= NBATCH*32) return;
  int bb = t >> 5, o = t & 31;
  float acc = b[o];
  for (int j=0;j<64;j++) acc = fmaf(t1[bb*64+j], W[j*32+o], acc);
  t2[t] = elu1(acc);
}

__global__ __launch_bounds__(256) void k_fc3(const float* __restrict__ t2,
    const float* __restrict__ W, const float* __restrict__ b, float* __restrict__ out){
  int t = blockIdx.x*256 + threadIdx.x;
  if (t >= NBATCH) return;
  float acc = b[0];
  for (int j=0;j<32;j++) acc = fmaf(t2[t*32+j], W[j], acc);
  out[t] = acc;
}

static inline int cdiv(long long a, int b){ return (int)((a + b - 1) / b); }

extern "C" void kernel_launch(void* const* d_in, const int* in_sizes, int n_in,
                              void* d_out, int out_size, void* d_ws, size_t ws_size,
                              hipStream_t stream) {
  const float* x0    = (const float*)d_in[0];
  const int*   ei    = (const int*)d_in[1];
  const float* ea    = (const float*)d_in[2];
  const int*   batch = (const int*)d_in[3];
  const int*   a2n   = (const int*)d_in[4];
  const int*   a2c   = (const int*)d_in[5];
  const float* iso2  = (const float*)d_in[6];
  const int*   ei2   = (const int*)d_in[7];
  const int*   b2arr = (const int*)d_in[8];
  const int*   a3n   = (const int*)d_in[9];
  const int*   a3c   = (const int*)d_in[10];
  const float* iso3  = (const float*)d_in[11];
  const int*   ei3   = (const int*)d_in[12];
  const int*   b3arr = (const int*)d_in[13];
  const float* nnp[3][6];
  for (int c=0;c<3;c++) for (int p=0;p<6;p++) nnp[c][p] = (const float*)d_in[14 + 6*c + p];
  const float* c4W[3]; const float* c5W[3]; const float* c6W[3]; const float* c7W[3];
  for (int p=0;p<3;p++){ c4W[p]=(const float*)d_in[32+p]; c5W[p]=(const float*)d_in[35+p];
                         c6W[p]=(const float*)d_in[38+p]; c7W[p]=(const float*)d_in[41+p]; }
  const float* fc1W=(const float*)d_in[44]; const float* fc1b=(const float*)d_in[45];
  const float* fc2W=(const float*)d_in[46]; const float* fc2b=(const float*)d_in[47];
  const float* fc3W=(const float*)d_in[48]; const float* fc3b=(const float*)d_in[49];
  float* outp = (float*)d_out;

  // ---- workspace carve ----
  char* ws = (char*)d_ws; size_t off = 0;
  auto alloc = [&](size_t bytes)->void*{ void* p = ws + off; off += (bytes + 255) & ~(size_t)255; return p; };
  const size_t SZ_R0 = (size_t)92*1024*1024;
  char* r0 = (char*)alloc(SZ_R0);
  // phase-1 view (NNConv): W2p 1MB | prepB 64KB | bterm 4MB | prep 4MB | msg 8MB
  f16*   W2p   = (f16*)r0;
  f16*   prepB = (f16*)(r0 + 2*1024*1024);
  float* bterm = (float*)(r0 + 2*1024*1024 + 64*1024);
  float* prep  = (float*)(r0 + 2*1024*1024 + 64*1024 + (size_t)NN*64*4);
  f16*   msg16 = (f16*)  (r0 + 2*1024*1024 + 64*1024 + (size_t)NN*64*8);
  // phase-2 view (written only after all NNConvs + gathers complete)
  size_t o2 = 0;
  auto a2 = [&](size_t bytes)->char*{ char* p = r0 + o2; o2 += (bytes + 255) & ~(size_t)255; return p; };
  f16*   h16   = (f16*)  a2((size_t)2*NC2*128*2);  // 32 MB
  f16*   y16   = (f16*)  a2((size_t)2*NC2*64*2);   // 16 MB
  f16*   rbuf16= (f16*)  a2((size_t)2*NC2*64*2);   // 16 MB
  f16*   g16   = (f16*)  a2((size_t)2*NC2*64*2);   // 16 MB
  f16*   BpGc  = (f16*)  a2((size_t)49152*2);      // 96 KB
  int*   ldegA = (int*)  a2((size_t)4*NC2*4);
  int*   ldegD = ldegA + 2*NC2;
  int*   ptrA  = (int*)  a2((size_t)2*NC2*4);
  int*   curA  = (int*)  a2((size_t)2*NC2*4);
  int*   ptrD  = (int*)  a2((size_t)2*NC2*4);
  int*   curD  = (int*)  a2((size_t)2*NC2*4);
  int*   ans2  = (int*)  a2((size_t)A2N*4);
  int*   ans3  = (int*)  a2((size_t)A3N*4);
  int*   dsrc2 = (int*)  a2((size_t)ELV*4);
  int*   dsrc3 = (int*)  a2((size_t)ELV*4);
  f16*   fin2  = h16;                       // layer-2 outputs reuse h16 region
  f16*   fin3  = h16 + (size_t)NC2*64;
  // persistent
  f16*   x016  = (f16*)  alloc((size_t)NN*16*2);
  f16*   hA16  = (f16*)  alloc((size_t)NN*32*2);
  f16*   hB16  = (f16*)  alloc((size_t)NN*64*2);
  f16*   hC16  = (f16*)  alloc((size_t)NN*64*2);
  int*   deg1  = (int*)  alloc((size_t)2*NN*4);
  int*   ptr1  = (int*)  alloc((size_t)2*NN*4);
  int*   cur1  = (int*)  alloc((size_t)2*NN*4);
  int*   eids  = (int*)  alloc((size_t)E1N*4);
  int*   srcs  = (int*)  alloc((size_t)E1N*4);
  int*   dpos  = (int*)  alloc((size_t)E1N*4);
  int*   parts = (int*)  alloc((size_t)512*4);
  float* x123  = (float*)alloc((size_t)NBATCH*192*4);
  float* t1    = (float*)alloc((size_t)NBATCH*64*4);
  float* t2    = (float*)alloc((size_t)NBATCH*32*4);
  (void)ws_size; (void)n_in; (void)in_sizes; (void)out_size;

  auto scan = [&](const int* dg, int totalN, int segs, int* ptr, int* cur){
    int nb = totalN/256/segs;
    k_scan1<<<totalN/256,256,0,stream>>>(dg, ptr, parts);
    k_scan2seg<<<segs,256,0,stream>>>(parts, nb);
    k_scan3<<<totalN/256,256,0,stream>>>(parts, ptr, cur);
  };

  // ---- level-1 CSR: src-sorted edges + dst-CSR of positions (one pass) ----
  hipMemsetAsync(deg1, 0, (size_t)2*NN*4, stream);
  k_count_edge_dual<<<cdiv(E1N,256),256,0,stream>>>(ei, deg1);
  scan(deg1, 2*NN, 2, ptr1, cur1);
  k_fill_edge_dual<<<cdiv(E1N,256),256,0,stream>>>(ei, cur1, eids, srcs, dpos);
  k_cvt16<<<cdiv((long long)NN*16,256),256,0,stream>>>(x0, x016, NN*16);

  // ---- NNConv x3 (fused v6 + msg gather) ----
  auto run_nnconv = [&](const f16* xin16, int mi, int mo,
                        const float* const* P, f16* out16){
    const float* W1=P[0]; const float* b1=P[1]; const float* W2=P[2];
    const float* b2=P[3]; const float* root=P[4]; const float* bias=P[5];
    const int S = (mi > 32) ? 2 : 1;
    const int NB = (2*mo)/16;
    k_packPrep<<<cdiv((long long)NB*S*512,256),256,0,stream>>>(root, b2, prepB, mi, mo, S, NB);
    if (mi==16)      k_prep_mfma<16,1,4,32><<<NN/64,256,0,stream>>>(xin16, prepB, bias, prep, bterm);
    else if (mi==32) k_prep_mfma<32,1,8,64><<<NN/64,256,0,stream>>>(xin16, prepB, bias, prep, bterm);
    else             k_prep_mfma<64,2,8,64><<<NN/64,256,0,stream>>>(xin16, prepB, bias, prep, bterm);
    k_w2pack_full<<<cdiv((long long)mo*8*S*512,256),256,0,stream>>>(W2, W2p, mi, mo, S);
    if (mi==16)      k_nnconv_fused6<16,1,32><<<NN/16,256,0,stream>>>(xin16, W2p, ptr1, cur1, srcs, eids, ea, W1, b1, bterm, msg16);
    else if (mi==32) k_nnconv_fused6<32,1,64><<<NN/16,256,0,stream>>>(xin16, W2p, ptr1, cur1, srcs, eids, ea, W1, b1, bterm, msg16);
    else             k_nnconv_fused6<64,2,64><<<NN/16,256,0,stream>>>(xin16, W2p, ptr1, cur1, srcs, eids, ea, W1, b1, bterm, msg16);
    if (mo==32) k_msg_gather<32><<<NN/8,256,0,stream>>>(ptr1+NN, cur1+NN, dpos, msg16, prep, out16);
    else        k_msg_gather<64><<<NN/4,256,0,stream>>>(ptr1+NN, cur1+NN, dpos, msg16, prep, out16);
  };
  run_nnconv(x016, 16, 32, nnp[0], hA16);
  run_nnconv(hA16, 32, 64, nnp[1], hB16);
  run_nnconv(hB16, 64, 64, nnp[2], hC16);

  // ---- level-2/3 CSR builds (dual) ----
  hipMemsetAsync(ldegA, 0, (size_t)4*NC2*4, stream);
  k_count_assign_dual<<<cdiv((long long)(A2N+A3N),256),256,0,stream>>>(a2c, a3c, ldegA);
  scan(ldegA, 2*NC2, 2, ptrA, curA);
  k_fill_assign_dual<<<cdiv((long long)(A2N+A3N),256),256,0,stream>>>(a2n, a2c, a3n, a3c, curA, ans2, ans3);
  k_count_dst_dual<<<cdiv((long long)2*ELV,256),256,0,stream>>>(ei2, ei3, ldegD);
  scan(ldegD, 2*NC2, 2, ptrD, curD);
  k_fill_dst_dual<<<cdiv((long long)2*ELV,256),256,0,stream>>>(ei2, ei3, curD, dsrc2, dsrc3);

  // ---- levels compute (dual launches) ----
  k_pool_gather_dual<<<2*NC2/4,256,0,stream>>>(ptrA, curA, ans2, ans3, hC16, iso2, iso3, h16);
  k_packB_all<<<cdiv(49152,256),256,0,stream>>>(c4W[0], c4W[1], c5W[0], c5W[1],
                                                c6W[0], c6W[1], c7W[0], c7W[1], BpGc);
  k_gc_mfma_dual<4><<<2*NC2/64,256,0,stream>>>(h16, BpGc, BP_O4, BP_O6, c4W[2], c6W[2], y16, rbuf16);
  k_gc_gather_dual<<<2*NC2/4,256,0,stream>>>(ptrD, curD, dsrc2, dsrc3, y16, rbuf16, g16);
  k_gc_mfma_dual<2><<<2*NC2/64,256,0,stream>>>(g16, BpGc, BP_O5, BP_O7, c5W[2], c7W[2], y16, rbuf16);
  k_gc_gather_dual<<<2*NC2/4,256,0,stream>>>(ptrD, curD, dsrc2, dsrc3, y16, rbuf16, fin2);

  // ---- batch sums (3 segments in one launch) + FC head ----
  k_batchsum3<<<3*NBATCH,256,0,stream>>>(batch, b2arr, b3arr, hC16, fin2, fin3, x123);
  k_fc1<<<cdiv((long long)NBATCH*64,256),256,0,stream>>>(x123, fc1W, fc1b, t1);
  k_fc2<<<cdiv((long long)NBATCH*32,256),256,0,stream>>>(t1, fc2W, fc2b, t2);
  k_fc3<<<cdiv(NBATCH,256),256,0,stream>>>(t2, fc3W, fc3b, outp);
}

// Round 12
// 737.935 us; speedup vs baseline: 1.4112x; 1.4112x over previous
//
#include <hip/hip_runtime.h>
#include <math.h>

#define NN 16384      // nodes
#define E1N 65536     // edges level 1
#define NBATCH 256
#define NC2 65536     // clusters (level 2 and level 3)
#define A2N 131072
#define A3N 196608
#define ELV 262144    // edges per level graph
#define KH 128        // edge-MLP hidden
#define OCS 136       // oc stride (f16)
#define MNSTR 1092    // M node stride (f16) — R8-verified low-conflict
#define ECAP 96       // edges per super-tile

typedef _Float16 f16;
typedef _Float16 f16x2 __attribute__((ext_vector_type(2)));
typedef _Float16 f16x4 __attribute__((ext_vector_type(4)));
typedef _Float16 f16x8 __attribute__((ext_vector_type(8)));
typedef float    f32x4 __attribute__((ext_vector_type(4)));

__device__ __forceinline__ float elu1(float x){ return x > 0.f ? x : expm1f(x); }

__device__ __forceinline__ float dot2acc(f16x2 a, f16x2 b, float c){
#if __has_builtin(__builtin_amdgcn_fdot2)
  return __builtin_amdgcn_fdot2(a, b, c, false);
#else
  return fmaf((float)a[0], (float)b[0], fmaf((float)a[1], (float)b[1], c));
#endif
}

// ---------------- segmented 3-phase scan ----------------
__global__ __launch_bounds__(256) void k_scan1(const int* __restrict__ deg,
    int* __restrict__ ptr, int* __restrict__ partials){
  __shared__ int buf[256];
  int i = blockIdx.x*256 + threadIdx.x, t = threadIdx.x;
  int v = deg[i];
  buf[t] = v; __syncthreads();
  for (int o = 1; o < 256; o <<= 1){
    int x = (t >= o) ? buf[t-o] : 0;
    __syncthreads(); buf[t] += x; __syncthreads();
  }
  ptr[i] = buf[t] - v;
  if (t == 255) partials[blockIdx.x] = buf[255];
}

__global__ __launch_bounds__(256) void k_scan2seg(int* __restrict__ partials, int nb){
  __shared__ int buf[256];
  int t = threadIdx.x, base = blockIdx.x*nb;
  int v = (t < nb) ? partials[base + t] : 0;
  buf[t] = v; __syncthreads();
  for (int o = 1; o < 256; o <<= 1){
    int x = (t >= o) ? buf[t-o] : 0;
    __syncthreads(); buf[t] += x; __syncthreads();
  }
  if (t < nb) partials[base + t] = buf[t] - v;
}

__global__ __launch_bounds__(256) void k_scan3(const int* __restrict__ partials,
    int* __restrict__ ptr, int* __restrict__ cur){
  int i = blockIdx.x*256 + threadIdx.x;
  int v = ptr[i] + partials[blockIdx.x];
  ptr[i] = v; cur[i] = v;
}

// ---------------- level-1 CSR (src + dst in one pass) ----------------
__global__ __launch_bounds__(256) void k_count_edge_dual(const int* __restrict__ ei, int* __restrict__ deg){
  int e = blockIdx.x*256 + threadIdx.x;
  if (e >= E1N) return;
  atomicAdd(&deg[ei[e]], 1);
  atomicAdd(&deg[NN + ei[E1N + e]], 1);
}

__global__ __launch_bounds__(256) void k_fill_edge_dual(const int* __restrict__ ei, int* __restrict__ cur,
    int* __restrict__ eids, int* __restrict__ srcs, int* __restrict__ dpos){
  int e = blockIdx.x*256 + threadIdx.x;
  if (e >= E1N) return;
  int s = ei[e], d = ei[E1N + e];
  int p = atomicAdd(&cur[s], 1);
  eids[p] = e; srcs[p] = s;
  int p2 = atomicAdd(&cur[NN + d], 1);
  dpos[p2] = p;
}

// ---------------- level-2/3 CSR (dual) ----------------
__global__ __launch_bounds__(256) void k_count_assign_dual(const int* __restrict__ a2c,
    const int* __restrict__ a3c, int* __restrict__ ldegA){
  int i = blockIdx.x*256 + threadIdx.x;
  if (i < A2N) atomicAdd(&ldegA[a2c[i]], 1);
  else if (i < A2N + A3N) atomicAdd(&ldegA[NC2 + a3c[i - A2N]], 1);
}

__global__ __launch_bounds__(256) void k_fill_assign_dual(const int* __restrict__ a2n,
    const int* __restrict__ a2c, const int* __restrict__ a3n, const int* __restrict__ a3c,
    int* __restrict__ curA, int* __restrict__ ans2, int* __restrict__ ans3){
  int i = blockIdx.x*256 + threadIdx.x;
  if (i < A2N){
    int p = atomicAdd(&curA[a2c[i]], 1); ans2[p] = a2n[i];
  } else if (i < A2N + A3N){
    int j = i - A2N;
    int p = atomicAdd(&curA[NC2 + a3c[j]], 1); ans3[p] = a3n[j];
  }
}

__global__ __launch_bounds__(256) void k_count_dst_dual(const int* __restrict__ ei2,
    const int* __restrict__ ei3, int* __restrict__ ldegD){
  int i = blockIdx.x*256 + threadIdx.x;
  if (i < ELV) atomicAdd(&ldegD[ei2[ELV + i]], 1);
  else if (i < 2*ELV) atomicAdd(&ldegD[NC2 + ei3[ELV + (i - ELV)]], 1);
}

__global__ __launch_bounds__(256) void k_fill_dst_dual(const int* __restrict__ ei2,
    const int* __restrict__ ei3, int* __restrict__ curD,
    int* __restrict__ dsrc2, int* __restrict__ dsrc3){
  int i = blockIdx.x*256 + threadIdx.x;
  if (i < ELV){
    int p = atomicAdd(&curD[ei2[ELV + i]], 1); dsrc2[p] = ei2[i];
  } else if (i < 2*ELV){
    int j = i - ELV;
    int p = atomicAdd(&curD[NC2 + ei3[ELV + j]], 1); dsrc3[p] = ei3[j];
  }
}

// ---------------- small converts ----------------
__global__ __launch_bounds__(256) void k_cvt16(const float* __restrict__ v, f16* __restrict__ o, int n){
  int t = blockIdx.x*256 + threadIdx.x;
  if (t < n) o[t] = (f16)v[t];
}

// ---------------- NNConv pieces ----------------
__global__ __launch_bounds__(256) void k_packPrep(const float* __restrict__ root,
    const float* __restrict__ b2, f16* __restrict__ Bp, int mi, int mo, int S, int NB){
  int t = blockIdx.x*256 + threadIdx.x;
  if (t >= NB*S*512) return;
  int j = t & 7, l = (t >> 3) & 63, cs = t >> 9;
  int s = cs % S, c = cs / S;
  int k_in = s*32 + ((l>>4)<<3) + j;
  int n = c*16 + (l & 15);
  float v = 0.f;
  if (k_in < mi) v = (n < mo) ? root[k_in*mo + n] : b2[k_in*mo + (n - mo)];
  Bp[t] = (f16)v;
}

// prep[n,o] = bias[o] + (x@root)[n,o]; bterm[n,o] = (x@b2)[n,o]
template<int MI, int S, int NB, int MO>
__global__ __launch_bounds__(256) void k_prep_mfma(const f16* __restrict__ A,
    const f16* __restrict__ Bp, const float* __restrict__ bias,
    float* __restrict__ prep, float* __restrict__ bterm){
  int l = threadIdx.x & 63, w = threadIdx.x >> 6;
  int r0 = blockIdx.x*64 + w*16;
  const f16* arow = A + (size_t)(r0 + (l & 15))*MI;
  f16x8 a[S];
  #pragma unroll
  for (int s=0;s<S;s++){
    int koff = s*32 + ((l>>4)<<3);
    if (koff < MI) a[s] = *(const f16x8*)(arow + koff);
    else           a[s] = (f16x8){0,0,0,0,0,0,0,0};
  }
  #pragma unroll
  for (int c=0;c<NB;c++){
    f32x4 acc = (f32x4){0.f,0.f,0.f,0.f};
    #pragma unroll
    for (int s=0;s<S;s++){
      f16x8 b = *(const f16x8*)(Bp + ((size_t)(c*S + s)*64 + l)*8);
      acc = __builtin_amdgcn_mfma_f32_16x16x32_f16(a[s], b, acc, 0, 0, 0);
    }
    int col = c*16 + (l & 15);
    #pragma unroll
    for (int r=0;r<4;r++){
      int row = r0 + ((l>>4)<<2) + r;
      if (col < MO) prep[(size_t)row*MO + col] = acc[r] + bias[col];
      else          bterm[(size_t)row*MO + (col - MO)] = acc[r];
    }
  }
}

__global__ __launch_bounds__(256) void k_w2pack_full(const float* __restrict__ W2,
    f16* __restrict__ Bp, int mi, int mo, int S){
  int t = blockIdx.x*256 + threadIdx.x;
  if (t >= mo*8*S*512) return;
  int j = t & 7, l = (t >> 3) & 63, cs = t >> 9;
  int s = cs % S, q = cs / S;
  int oc = q >> 3;
  int k  = (q & 7)*16 + (l & 15);
  int i  = s*32 + ((l>>4)<<3) + j;
  float v = (i < mi) ? W2[(size_t)k*mi*mo + (size_t)i*mo + oc] : 0.f;
  Bp[t] = (f16)v;
}

// FUSED NNConv v5 (R10-verified): 16 nodes/block, 8-oc chunks, MNSTR 1092.
// bterm staged to LDS; msg written to coalesced f16 buffer (no atomics).
template<int MI, int S, int MO>
__global__ __launch_bounds__(256) void k_nnconv_fused5(const f16* __restrict__ xin16,
    const f16* __restrict__ W2p,
    const int* __restrict__ rowptr, const int* __restrict__ rowend,
    const int* __restrict__ srcs, const int* __restrict__ eids,
    const float* __restrict__ ea, const float* __restrict__ W1,
    const float* __restrict__ b1,
    const float* __restrict__ bterm, f16* __restrict__ msg16){
  __shared__ __align__(16) f16   M[16*MNSTR];    // 34944 B
  __shared__ __align__(16) f16   hb[ECAP*OCS];   // 26112 B
  __shared__ __align__(16) float eas[ECAP*8];    //  3072 B
  __shared__ float bt[16*MO];                    // 4096/2048 B
  int t = threadIdx.x, l = t & 63, w = t >> 6;
  int n0 = blockIdx.x*16;
  int estart = rowptr[n0], eend = rowend[n0+15];
  if (estart >= eend) return;                    // block-uniform
  for (int idx = t; idx < 16*MO; idx += 256) bt[idx] = bterm[(size_t)n0*MO + idx];
  const f16* arow = xin16 + (size_t)(n0 + (l&15))*MI;
  f16x8 a[S];
  #pragma unroll
  for (int s=0;s<S;s++){
    int koff = s*32 + ((l>>4)<<3);
    if (koff < MI) a[s] = *(const f16x8*)(arow + koff);
    else           a[s] = (f16x8){0,0,0,0,0,0,0,0};
  }
  const int NCHUNK = MO/8;
  int oc = t & 7, eslot = t >> 3;                // 32 edge slots
  for (int ebase = estart; ebase < eend; ebase += ECAP){
    int ecnt = eend - ebase; if (ecnt > ECAP) ecnt = ECAP;
    // ---- stage ea rows ----
    for (int idx = t; idx < ecnt*8; idx += 256){
      int e_ = idx >> 3, i = idx & 7;
      eas[idx] = (i < 7) ? ea[(size_t)eids[ebase + e_]*7 + i] : 0.f;
    }
    __syncthreads();
    // ---- fused edge-MLP -> hb ----
    for (int idx = t; idx < ecnt*32; idx += 256){
      int e_ = idx >> 5, p = idx & 31;
      int k0 = p*4;
      const float* xr = &eas[e_*8];
      float4 acc4 = *(const float4*)(b1 + k0);
      #pragma unroll
      for (int i=0;i<7;i++){
        float xv = xr[i];
        float4 wv = *(const float4*)(W1 + i*KH + k0);
        acc4.x = fmaf(xv, wv.x, acc4.x);
        acc4.y = fmaf(xv, wv.y, acc4.y);
        acc4.z = fmaf(xv, wv.z, acc4.z);
        acc4.w = fmaf(xv, wv.w, acc4.w);
      }
      f16x4 hv = { (f16)fmaxf(acc4.x,0.f), (f16)fmaxf(acc4.y,0.f),
                   (f16)fmaxf(acc4.z,0.f), (f16)fmaxf(acc4.w,0.f) };
      *(f16x4*)&hb[e_*OCS + k0] = hv;
    }
    __syncthreads();
    // ---- chunk loop ----
    for (int c = 0; c < NCHUNK; c++){
      #pragma unroll
      for (int tt = 0; tt < 16; tt++){
        int q = c*64 + w*16 + tt;
        f32x4 acc = (f32x4){0.f,0.f,0.f,0.f};
        #pragma unroll
        for (int s=0;s<S;s++){
          f16x8 b = *(const f16x8*)(W2p + ((size_t)(q*S + s)*64 + l)*8);
          acc = __builtin_amdgcn_mfma_f32_16x16x32_f16(a[s], b, acc, 0, 0, 0);
        }
        int ocl = w*2 + (tt>>3);
        int kpos = (tt&7)*16 + (l & 15);
        f16* mp = &M[ocl*OCS + kpos];
        #pragma unroll
        for (int r=0;r<4;r++)
          mp[(size_t)(((l>>4)<<2) + r)*MNSTR] = (f16)acc[r];
      }
      __syncthreads();
      // stage 2: consume edges -> msg (LDS only; coalesced store)
      #pragma unroll
      for (int r2 = 0; r2 < ECAP/32; r2++){
        int ee = r2*32 + eslot;
        if (ee < ecnt){
          int e = ebase + ee;
          int s_ = srcs[e];
          int ln = s_ - n0;
          float acc = bt[ln*MO + c*8 + oc];
          const f16* mrow = &M[(size_t)ln*MNSTR + oc*OCS];
          const f16* hrow = &hb[ee*OCS];
          #pragma unroll 4
          for (int kk=0; kk<16; kk++){
            f16x8 h8 = *(const f16x8*)(hrow + kk*8);
            f16x4 m0 = *(const f16x4*)(mrow + kk*8);
            f16x4 m1 = *(const f16x4*)(mrow + kk*8 + 4);
            acc = dot2acc((f16x2){h8[0],h8[1]}, (f16x2){m0[0],m0[1]}, acc);
            acc = dot2acc((f16x2){h8[2],h8[3]}, (f16x2){m0[2],m0[3]}, acc);
            acc = dot2acc((f16x2){h8[4],h8[5]}, (f16x2){m1[0],m1[1]}, acc);
            acc = dot2acc((f16x2){h8[6],h8[7]}, (f16x2){m1[2],m1[3]}, acc);
          }
          msg16[(size_t)e*MO + c*8 + oc] = (f16)acc;
        }
      }
      __syncthreads();
    }
  }
}

// dst-CSR gather of conv messages, 4-wide batched loads (latency hiding):
// out16[n,o] = elu(prep[n,o] + sum msg[dpos[p], o])
template<int MO>
__global__ __launch_bounds__(256) void k_msg_gather(const int* __restrict__ dptr,
    const int* __restrict__ dend, const int* __restrict__ dpos,
    const f16* __restrict__ msg, const float* __restrict__ prep,
    f16* __restrict__ out16){
  int t = threadIdx.x, l = t & 63, w = t >> 6;
  int n, o;
  if (MO == 64){ n = blockIdx.x*4 + w; o = l; }
  else         { n = blockIdx.x*8 + w*2 + (l>>5); o = l & 31; }
  int st = dptr[n], en = dend[n];
  float acc = prep[(size_t)n*MO + o];
  int p = st;
  for (; p + 4 <= en; p += 4){
    int q0 = dpos[p], q1 = dpos[p+1], q2 = dpos[p+2], q3 = dpos[p+3];
    float v0 = (float)msg[(size_t)q0*MO + o];
    float v1 = (float)msg[(size_t)q1*MO + o];
    float v2 = (float)msg[(size_t)q2*MO + o];
    float v3 = (float)msg[(size_t)q3*MO + o];
    acc += (v0 + v1) + (v2 + v3);
  }
  for (; p < en; p++) acc += (float)msg[(size_t)dpos[p]*MO + o];
  out16[(size_t)n*MO + o] = (f16)elu1(acc);
}

// ---------------- pooling via cluster-CSR, dual-level, 4-wide ----------------
__global__ __launch_bounds__(256) void k_pool_gather_dual(const int* __restrict__ aptr,
    const int* __restrict__ aend, const int* __restrict__ ans2, const int* __restrict__ ans3,
    const f16* __restrict__ h, const float* __restrict__ iso2, const float* __restrict__ iso3,
    f16* __restrict__ h16){
  int l = threadIdx.x & 63, w = threadIdx.x >> 6;
  int cg = blockIdx.x*4 + w;               // [0, 2*NC2)
  int lvl = cg >= NC2;
  int c = cg - lvl*NC2;
  const int* ans = lvl ? ans3 : ans2;
  const float* iso = lvl ? iso3 : iso2;
  int st = aptr[cg], en = aend[cg];
  float acc = 0.f;
  int e = st;
  for (; e + 4 <= en; e += 4){
    int n0 = ans[e], n1 = ans[e+1], n2 = ans[e+2], n3 = ans[e+3];
    float v0 = (float)h[(size_t)n0*64 + l];
    float v1 = (float)h[(size_t)n1*64 + l];
    float v2 = (float)h[(size_t)n2*64 + l];
    float v3 = (float)h[(size_t)n3*64 + l];
    acc += (v0 + v1) + (v2 + v3);
  }
  for (; e < en; e++) acc += (float)h[(size_t)ans[e]*64 + l];
  int cnt = en - st;
  float val = (cnt > 0) ? acc / (float)cnt : 0.f;
  h16[(size_t)cg*128 + l] = (f16)val;
  h16[(size_t)cg*128 + 64 + l] = (f16)iso[(size_t)c*64 + l];
}

// ---------------- GraphConv (dual-level) ----------------
#define BP_O4 0
#define BP_O5 16384
#define BP_O6 24576
#define BP_O7 40960
__global__ __launch_bounds__(256) void k_packB_all(
    const float* __restrict__ W4r, const float* __restrict__ W4o,
    const float* __restrict__ W5r, const float* __restrict__ W5o,
    const float* __restrict__ W6r, const float* __restrict__ W6o,
    const float* __restrict__ W7r, const float* __restrict__ W7o,
    f16* __restrict__ Bp){
  int t = blockIdx.x*256 + threadIdx.x;
  const float *Wrel, *Wroot; int S, base;
  if      (t < BP_O5){ Wrel=W4r; Wroot=W4o; S=4; base=BP_O4; }
  else if (t < BP_O6){ Wrel=W5r; Wroot=W5o; S=2; base=BP_O5; }
  else if (t < BP_O7){ Wrel=W6r; Wroot=W6o; S=4; base=BP_O6; }
  else if (t < 49152){ Wrel=W7r; Wroot=W7o; S=2; base=BP_O7; }
  else return;
  int u = t - base;
  int j = u & 7, l = (u >> 3) & 63, cs = u >> 9;
  int s = cs % S, c = cs / S;
  int k = s*32 + ((l>>4)<<3) + j;
  int n = (c<<4) + (l & 15);
  float v = (n < 64) ? Wrel[k*64 + n] : Wroot[k*64 + (n - 64)];
  Bp[t] = (f16)v;
}

template<int S>
__global__ __launch_bounds__(256) void k_gc_mfma_dual(const f16* __restrict__ Abase,
    const f16* __restrict__ Bp, int bpo2, int bpo3,
    const float* __restrict__ bias2, const float* __restrict__ bias3,
    f16* __restrict__ y16, f16* __restrict__ rbuf16){
  const int half = NC2/64;
  int lvl = blockIdx.x >= half;
  int bloc = blockIdx.x - lvl*half;
  const f16* A = Abase + (size_t)lvl*NC2*(S*32);
  const f16* B = Bp + (lvl ? bpo3 : bpo2);
  const float* bias = lvl ? bias3 : bias2;
  f16* y  = y16 + (size_t)lvl*NC2*64;
  f16* rb = rbuf16 + (size_t)lvl*NC2*64;
  int l = threadIdx.x & 63, w = threadIdx.x >> 6;
  int r0 = bloc*64 + w*16;
  const f16* arow = A + (size_t)(r0 + (l & 15))*(S*32);
  f16x8 a[S];
  #pragma unroll
  for (int s=0;s<S;s++) a[s] = *(const f16x8*)(arow + s*32 + ((l>>4)<<3));
  f32x4 acc[8];
  #pragma unroll
  for (int c=0;c<8;c++) acc[c] = (f32x4){0.f,0.f,0.f,0.f};
  #pragma unroll
  for (int c=0;c<8;c++){
    #pragma unroll
    for (int s=0;s<S;s++){
      f16x8 b = *(const f16x8*)(B + ((size_t)(c*S + s)*64 + l)*8);
      acc[c] = __builtin_amdgcn_mfma_f32_16x16x32_f16(a[s], b, acc[c], 0, 0, 0);
    }
  }
  #pragma unroll
  for (int c=0;c<8;c++){
    int col = c*16 + (l & 15);
    #pragma unroll
    for (int r=0;r<4;r++){
      int row = r0 + ((l>>4)<<2) + r;
      if (col < 64) y[(size_t)row*64 + col] = (f16)acc[c][r];
      else          rb[(size_t)row*64 + (col-64)] = (f16)(acc[c][r] + bias[col-64]);
    }
  }
}

__global__ __launch_bounds__(256) void k_gc_gather_dual(const int* __restrict__ dptrD,
    const int* __restrict__ dcurD, const int* __restrict__ dsrc2, const int* __restrict__ dsrc3,
    const f16* __restrict__ y16, const f16* __restrict__ rbuf16,
    f16* __restrict__ obase){
  int l = threadIdx.x & 63, w = threadIdx.x >> 6;
  int ng = blockIdx.x*4 + w;               // [0, 2*NC2)
  int lvl = ng >= NC2;
  int n = ng - lvl*NC2;
  const int* dsrc = lvl ? dsrc3 : dsrc2;
  const f16* y  = y16 + (size_t)lvl*NC2*64;
  const f16* rb = rbuf16 + (size_t)lvl*NC2*64;
  f16* o = obase + (size_t)lvl*NC2*64;
  int st = dptrD[ng], en = dcurD[ng];
  float acc = (float)rb[(size_t)n*64 + l];
  int e = st;
  for (; e + 4 <= en; e += 4){
    int s0 = dsrc[e], s1 = dsrc[e+1], s2 = dsrc[e+2], s3 = dsrc[e+3];
    float v0 = (float)y[(size_t)s0*64 + l];
    float v1 = (float)y[(size_t)s1*64 + l];
    float v2 = (float)y[(size_t)s2*64 + l];
    float v3 = (float)y[(size_t)s3*64 + l];
    acc += (v0 + v1) + (v2 + v3);
  }
  for (; e < en; e++) acc += (float)y[(size_t)dsrc[e]*64 + l];
  o[(size_t)n*64 + l] = (f16)elu1(acc);
}

// ---------------- 3-way sorted-segment batch sum ----------------
__device__ __forceinline__ int lowerb(const int* __restrict__ a, int n, int key){
  int lo = 0, hi = n;
  while (lo < hi){ int m = (lo + hi) >> 1; if (a[m] < key) lo = m + 1; else hi = m; }
  return lo;
}

__global__ __launch_bounds__(256) void k_batchsum3(const int* __restrict__ b1,
    const int* __restrict__ b2, const int* __restrict__ b3,
    const f16* __restrict__ s1, const f16* __restrict__ s2, const f16* __restrict__ s3,
    float* __restrict__ x123){
  __shared__ float red[4][64];
  int seg = blockIdx.x >> 8, b = blockIdx.x & 255;
  const int* batch = (seg==0) ? b1 : ((seg==1) ? b2 : b3);
  const f16* src   = (seg==0) ? s1 : ((seg==1) ? s2 : s3);
  int nn = (seg==0) ? NN : NC2;
  int lo = lowerb(batch, nn, b);
  int hi = lowerb(batch, nn, b+1);
  int col = threadIdx.x & 63, wq = threadIdx.x >> 6;
  float acc = 0.f;
  for (int n = lo + wq; n < hi; n += 4) acc += (float)src[(size_t)n*64 + col];
  red[wq][col] = acc;
  __syncthreads();
  if (threadIdx.x < 64){
    float s = red[0][threadIdx.x] + red[1][threadIdx.x] + red[2][threadIdx.x] + red[3][threadIdx.x];
    x123[b*192 + seg*64 + threadIdx.x] = s;
  }
}

// ---------------- FC head ----------------
__global__ __launch_bounds__(256) void k_fc1(const float* __restrict__ x123,
    const float* __restrict__ W, const float* __restrict__ b, float* __restrict__ t1){
  int t = blockIdx.x*256 + threadIdx.x;
  if (t >= NBATCH*64) return;
  int bb = t >> 6, o = t & 63;
  const float* xr = x123 + bb*192;
  float acc = b[o];
  for (int j=0;j<192;j++) acc = fmaf(xr[j], W[j*64+o] + W[(192+j)*64+o], acc);
  t1[t] = elu1(acc);
}

__global__ __launch_bounds__(256) void k_fc2(const float* __restrict__ t1,
    const float* __restrict__ W, const float* __restrict__ b, float* __restrict__ t2){
  int t = blockIdx.x*256 + threadIdx.x;
  if (t >= NBATCH*32) return;
  int bb = t >> 5, o = t & 31;
  float acc = b[o];
  for (int j=0;j<64;j++) acc = fmaf(t1[bb*64+j], W[j*32+o], acc);
  t2[t] = elu1(acc);
}

__global__ __launch_bounds__(256) void k_fc3(const float* __restrict__ t2,
    const float* __restrict__ W, const float* __restrict__ b, float* __restrict__ out){
  int t = blockIdx.x*256 + threadIdx.x;
  if (t >= NBATCH) return;
  float acc = b[0];
  for (int j=0;j<32;j++) acc = fmaf(t2[t*32+j], W[j], acc);
  out[t] = acc;
}

static inline int cdiv(long long a, int b){ return (int)((a + b - 1) / b); }

extern "C" void kernel_launch(void* const* d_in, const int* in_sizes, int n_in,
                              void* d_out, int out_size, void* d_ws, size_t ws_size,
                              hipStream_t stream) {
  const float* x0    = (const float*)d_in[0];
  const int*   ei    = (const int*)d_in[1];
  const float* ea    = (const float*)d_in[2];
  const int*   batch = (const int*)d_in[3];
  const int*   a2n   = (const int*)d_in[4];
  const int*   a2c   = (const int*)d_in[5];
  const float* iso2  = (const float*)d_in[6];
  const int*   ei2   = (const int*)d_in[7];
  const int*   b2arr = (const int*)d_in[8];
  const int*   a3n   = (const int*)d_in[9];
  const int*   a3c   = (const int*)d_in[10];
  const float* iso3  = (const float*)d_in[11];
  const int*   ei3   = (const int*)d_in[12];
  const int*   b3arr = (const int*)d_in[13];
  const float* nnp[3][6];
  for (int c=0;c<3;c++) for (int p=0;p<6;p++) nnp[c][p] = (const float*)d_in[14 + 6*c + p];
  const float* c4W[3]; const float* c5W[3]; const float* c6W[3]; const float* c7W[3];
  for (int p=0;p<3;p++){ c4W[p]=(const float*)d_in[32+p]; c5W[p]=(const float*)d_in[35+p];
                         c6W[p]=(const float*)d_in[38+p]; c7W[p]=(const float*)d_in[41+p]; }
  const float* fc1W=(const float*)d_in[44]; const float* fc1b=(const float*)d_in[45];
  const float* fc2W=(const float*)d_in[46]; const float* fc2b=(const float*)d_in[47];
  const float* fc3W=(const float*)d_in[48]; const float* fc3b=(const float*)d_in[49];
  float* outp = (float*)d_out;

  // ---- workspace carve ----
  char* ws = (char*)d_ws; size_t off = 0;
  auto alloc = [&](size_t bytes)->void*{ void* p = ws + off; off += (bytes + 255) & ~(size_t)255; return p; };
  const size_t SZ_R0 = (size_t)92*1024*1024;
  char* r0 = (char*)alloc(SZ_R0);
  // phase-1 view (NNConv): W2p 1MB | prepB 64KB | bterm 4MB | prep 4MB | msg 8MB
  f16*   W2p   = (f16*)r0;
  f16*   prepB = (f16*)(r0 + 2*1024*1024);
  float* bterm = (float*)(r0 + 2*1024*1024 + 64*1024);
  float* prep  = (float*)(r0 + 2*1024*1024 + 64*1024 + (size_t)NN*64*4);
  f16*   msg16 = (f16*)  (r0 + 2*1024*1024 + 64*1024 + (size_t)NN*64*8);
  // phase-2 view (written only after all NNConvs + gathers complete)
  size_t o2 = 0;
  auto a2 = [&](size_t bytes)->char*{ char* p = r0 + o2; o2 += (bytes + 255) & ~(size_t)255; return p; };
  f16*   h16   = (f16*)  a2((size_t)2*NC2*128*2);  // 32 MB
  f16*   y16   = (f16*)  a2((size_t)2*NC2*64*2);   // 16 MB
  f16*   rbuf16= (f16*)  a2((size_t)2*NC2*64*2);   // 16 MB
  f16*   g16   = (f16*)  a2((size_t)2*NC2*64*2);   // 16 MB
  f16*   BpGc  = (f16*)  a2((size_t)49152*2);      // 96 KB
  int*   ldegA = (int*)  a2((size_t)4*NC2*4);
  int*   ldegD = ldegA + 2*NC2;
  int*   ptrA  = (int*)  a2((size_t)2*NC2*4);
  int*   curA  = (int*)  a2((size_t)2*NC2*4);
  int*   ptrD  = (int*)  a2((size_t)2*NC2*4);
  int*   curD  = (int*)  a2((size_t)2*NC2*4);
  int*   ans2  = (int*)  a2((size_t)A2N*4);
  int*   ans3  = (int*)  a2((size_t)A3N*4);
  int*   dsrc2 = (int*)  a2((size_t)ELV*4);
  int*   dsrc3 = (int*)  a2((size_t)ELV*4);
  f16*   fin2  = h16;                       // layer-2 outputs reuse h16 region
  f16*   fin3  = h16 + (size_t)NC2*64;
  // persistent
  f16*   x016  = (f16*)  alloc((size_t)NN*16*2);
  f16*   hA16  = (f16*)  alloc((size_t)NN*32*2);
  f16*   hB16  = (f16*)  alloc((size_t)NN*64*2);
  f16*   hC16  = (f16*)  alloc((size_t)NN*64*2);
  int*   deg1  = (int*)  alloc((size_t)2*NN*4);
  int*   ptr1  = (int*)  alloc((size_t)2*NN*4);
  int*   cur1  = (int*)  alloc((size_t)2*NN*4);
  int*   eids  = (int*)  alloc((size_t)E1N*4);
  int*   srcs  = (int*)  alloc((size_t)E1N*4);
  int*   dpos  = (int*)  alloc((size_t)E1N*4);
  int*   parts = (int*)  alloc((size_t)512*4);
  float* x123  = (float*)alloc((size_t)NBATCH*192*4);
  float* t1    = (float*)alloc((size_t)NBATCH*64*4);
  float* t2    = (float*)alloc((size_t)NBATCH*32*4);
  (void)ws_size; (void)n_in; (void)in_sizes; (void)out_size;

  auto scan = [&](const int* dg, int totalN, int segs, int* ptr, int* cur){
    int nb = totalN/256/segs;
    k_scan1<<<totalN/256,256,0,stream>>>(dg, ptr, parts);
    k_scan2seg<<<segs,256,0,stream>>>(parts, nb);
    k_scan3<<<totalN/256,256,0,stream>>>(parts, ptr, cur);
  };

  // ---- level-1 CSR: src-sorted edges + dst-CSR of positions (one pass) ----
  hipMemsetAsync(deg1, 0, (size_t)2*NN*4, stream);
  k_count_edge_dual<<<cdiv(E1N,256),256,0,stream>>>(ei, deg1);
  scan(deg1, 2*NN, 2, ptr1, cur1);
  k_fill_edge_dual<<<cdiv(E1N,256),256,0,stream>>>(ei, cur1, eids, srcs, dpos);
  k_cvt16<<<cdiv((long long)NN*16,256),256,0,stream>>>(x0, x016, NN*16);

  // ---- NNConv x3 (fused v5 + 4-wide msg gather) ----
  auto run_nnconv = [&](const f16* xin16, int mi, int mo,
                        const float* const* P, f16* out16){
    const float* W1=P[0]; const float* b1=P[1]; const float* W2=P[2];
    const float* b2=P[3]; const float* root=P[4]; const float* bias=P[5];
    const int S = (mi > 32) ? 2 : 1;
    const int NB = (2*mo)/16;
    k_packPrep<<<cdiv((long long)NB*S*512,256),256,0,stream>>>(root, b2, prepB, mi, mo, S, NB);
    if (mi==16)      k_prep_mfma<16,1,4,32><<<NN/64,256,0,stream>>>(xin16, prepB, bias, prep, bterm);
    else if (mi==32) k_prep_mfma<32,1,8,64><<<NN/64,256,0,stream>>>(xin16, prepB, bias, prep, bterm);
    else             k_prep_mfma<64,2,8,64><<<NN/64,256,0,stream>>>(xin16, prepB, bias, prep, bterm);
    k_w2pack_full<<<cdiv((long long)mo*8*S*512,256),256,0,stream>>>(W2, W2p, mi, mo, S);
    if (mi==16)      k_nnconv_fused5<16,1,32><<<NN/16,256,0,stream>>>(xin16, W2p, ptr1, cur1, srcs, eids, ea, W1, b1, bterm, msg16);
    else if (mi==32) k_nnconv_fused5<32,1,64><<<NN/16,256,0,stream>>>(xin16, W2p, ptr1, cur1, srcs, eids, ea, W1, b1, bterm, msg16);
    else             k_nnconv_fused5<64,2,64><<<NN/16,256,0,stream>>>(xin16, W2p, ptr1, cur1, srcs, eids, ea, W1, b1, bterm, msg16);
    if (mo==32) k_msg_gather<32><<<NN/8,256,0,stream>>>(ptr1+NN, cur1+NN, dpos, msg16, prep, out16);
    else        k_msg_gather<64><<<NN/4,256,0,stream>>>(ptr1+NN, cur1+NN, dpos, msg16, prep, out16);
  };
  run_nnconv(x016, 16, 32, nnp[0], hA16);
  run_nnconv(hA16, 32, 64, nnp[1], hB16);
  run_nnconv(hB16, 64, 64, nnp[2], hC16);

  // ---- level-2/3 CSR builds (dual) ----
  hipMemsetAsync(ldegA, 0, (size_t)4*NC2*4, stream);
  k_count_assign_dual<<<cdiv((long long)(A2N+A3N),256),256,0,stream>>>(a2c, a3c, ldegA);
  scan(ldegA, 2*NC2, 2, ptrA, curA);
  k_fill_assign_dual<<<cdiv((long long)(A2N+A3N),256),256,0,stream>>>(a2n, a2c, a3n, a3c, curA, ans2, ans3);
  k_count_dst_dual<<<cdiv((long long)2*ELV,256),256,0,stream>>>(ei2, ei3, ldegD);
  scan(ldegD, 2*NC2, 2, ptrD, curD);
  k_fill_dst_dual<<<cdiv((long long)2*ELV,256),256,0,stream>>>(ei2, ei3, curD, dsrc2, dsrc3);

  // ---- levels compute (dual launches) ----
  k_pool_gather_dual<<<2*NC2/4,256,0,stream>>>(ptrA, curA, ans2, ans3, hC16, iso2, iso3, h16);
  k_packB_all<<<cdiv(49152,256),256,0,stream>>>(c4W[0], c4W[1], c5W[0], c5W[1],
                                                c6W[0], c6W[1], c7W[0], c7W[1], BpGc);
  k_gc_mfma_dual<4><<<2*NC2/64,256,0,stream>>>(h16, BpGc, BP_O4, BP_O6, c4W[2], c6W[2], y16, rbuf16);
  k_gc_gather_dual<<<2*NC2/4,256,0,stream>>>(ptrD, curD, dsrc2, dsrc3, y16, rbuf16, g16);
  k_gc_mfma_dual<2><<<2*NC2/64,256,0,stream>>>(g16, BpGc, BP_O5, BP_O7, c5W[2], c7W[2], y16, rbuf16);
  k_gc_gather_dual<<<2*NC2/4,256,0,stream>>>(ptrD, curD, dsrc2, dsrc3, y16, rbuf16, fin2);

  // ---- batch sums (3 segments in one launch) + FC head ----
  k_batchsum3<<<3*NBATCH,256,0,stream>>>(batch, b2arr, b3arr, hC16, fin2, fin3, x123);
  k_fc1<<<cdiv((long long)NBATCH*64,256),256,0,stream>>>(x123, fc1W, fc1b, t1);
  k_fc2<<<cdiv((long long)NBATCH*32,256),256,0,stream>>>(t1, fc2W, fc2b, t2);
  k_fc3<<<cdiv(NBATCH,256),256,0,stream>>>(t2, fc3W, fc3b, outp);
}

// Round 13
// 732.344 us; speedup vs baseline: 1.4220x; 1.0076x over previous
//
#include <hip/hip_runtime.h>
#include <math.h>

#define NN 16384      // nodes
#define E1N 65536     // edges level 1
#define NBATCH 256
#define NC2 65536     // clusters (level 2 and level 3)
#define A2N 131072
#define A3N 196608
#define ELV 262144    // edges per level graph
#define KH 128        // edge-MLP hidden
#define OCS 136       // oc stride (f16)
#define WNSTR 280     // v7 per-wave M node stride (f16): 16B-aligned, 140dw = 12 mod 32
#define ECAP 96       // edges per super-tile

typedef _Float16 f16;
typedef _Float16 f16x2 __attribute__((ext_vector_type(2)));
typedef _Float16 f16x4 __attribute__((ext_vector_type(4)));
typedef _Float16 f16x8 __attribute__((ext_vector_type(8)));
typedef float    f32x4 __attribute__((ext_vector_type(4)));

__device__ __forceinline__ float elu1(float x){ return x > 0.f ? x : expm1f(x); }

__device__ __forceinline__ float dot2acc(f16x2 a, f16x2 b, float c){
#if __has_builtin(__builtin_amdgcn_fdot2)
  return __builtin_amdgcn_fdot2(a, b, c, false);
#else
  return fmaf((float)a[0], (float)b[0], fmaf((float)a[1], (float)b[1], c));
#endif
}

// ---------------- segmented 3-phase scan ----------------
__global__ __launch_bounds__(256) void k_scan1(const int* __restrict__ deg,
    int* __restrict__ ptr, int* __restrict__ partials){
  __shared__ int buf[256];
  int i = blockIdx.x*256 + threadIdx.x, t = threadIdx.x;
  int v = deg[i];
  buf[t] = v; __syncthreads();
  for (int o = 1; o < 256; o <<= 1){
    int x = (t >= o) ? buf[t-o] : 0;
    __syncthreads(); buf[t] += x; __syncthreads();
  }
  ptr[i] = buf[t] - v;
  if (t == 255) partials[blockIdx.x] = buf[255];
}

__global__ __launch_bounds__(256) void k_scan2seg(int* __restrict__ partials, int nb){
  __shared__ int buf[256];
  int t = threadIdx.x, base = blockIdx.x*nb;
  int v = (t < nb) ? partials[base + t] : 0;
  buf[t] = v; __syncthreads();
  for (int o = 1; o < 256; o <<= 1){
    int x = (t >= o) ? buf[t-o] : 0;
    __syncthreads(); buf[t] += x; __syncthreads();
  }
  if (t < nb) partials[base + t] = buf[t] - v;
}

__global__ __launch_bounds__(256) void k_scan3(const int* __restrict__ partials,
    int* __restrict__ ptr, int* __restrict__ cur){
  int i = blockIdx.x*256 + threadIdx.x;
  int v = ptr[i] + partials[blockIdx.x];
  ptr[i] = v; cur[i] = v;
}

// ---------------- level-1 CSR (src + dst in one pass) ----------------
__global__ __launch_bounds__(256) void k_count_edge_dual(const int* __restrict__ ei, int* __restrict__ deg){
  int e = blockIdx.x*256 + threadIdx.x;
  if (e >= E1N) return;
  atomicAdd(&deg[ei[e]], 1);
  atomicAdd(&deg[NN + ei[E1N + e]], 1);
}

__global__ __launch_bounds__(256) void k_fill_edge_dual(const int* __restrict__ ei, int* __restrict__ cur,
    int* __restrict__ eids, int* __restrict__ srcs, int* __restrict__ dpos){
  int e = blockIdx.x*256 + threadIdx.x;
  if (e >= E1N) return;
  int s = ei[e], d = ei[E1N + e];
  int p = atomicAdd(&cur[s], 1);
  eids[p] = e; srcs[p] = s;
  int p2 = atomicAdd(&cur[NN + d], 1);
  dpos[p2] = p;
}

// ---------------- level-2/3 CSR (dual) ----------------
__global__ __launch_bounds__(256) void k_count_assign_dual(const int* __restrict__ a2c,
    const int* __restrict__ a3c, int* __restrict__ ldegA){
  int i = blockIdx.x*256 + threadIdx.x;
  if (i < A2N) atomicAdd(&ldegA[a2c[i]], 1);
  else if (i < A2N + A3N) atomicAdd(&ldegA[NC2 + a3c[i - A2N]], 1);
}

__global__ __launch_bounds__(256) void k_fill_assign_dual(const int* __restrict__ a2n,
    const int* __restrict__ a2c, const int* __restrict__ a3n, const int* __restrict__ a3c,
    int* __restrict__ curA, int* __restrict__ ans2, int* __restrict__ ans3){
  int i = blockIdx.x*256 + threadIdx.x;
  if (i < A2N){
    int p = atomicAdd(&curA[a2c[i]], 1); ans2[p] = a2n[i];
  } else if (i < A2N + A3N){
    int j = i - A2N;
    int p = atomicAdd(&curA[NC2 + a3c[j]], 1); ans3[p] = a3n[j];
  }
}

__global__ __launch_bounds__(256) void k_count_dst_dual(const int* __restrict__ ei2,
    const int* __restrict__ ei3, int* __restrict__ ldegD){
  int i = blockIdx.x*256 + threadIdx.x;
  if (i < ELV) atomicAdd(&ldegD[ei2[ELV + i]], 1);
  else if (i < 2*ELV) atomicAdd(&ldegD[NC2 + ei3[ELV + (i - ELV)]], 1);
}

__global__ __launch_bounds__(256) void k_fill_dst_dual(const int* __restrict__ ei2,
    const int* __restrict__ ei3, int* __restrict__ curD,
    int* __restrict__ dsrc2, int* __restrict__ dsrc3){
  int i = blockIdx.x*256 + threadIdx.x;
  if (i < ELV){
    int p = atomicAdd(&curD[ei2[ELV + i]], 1); dsrc2[p] = ei2[i];
  } else if (i < 2*ELV){
    int j = i - ELV;
    int p = atomicAdd(&curD[NC2 + ei3[ELV + j]], 1); dsrc3[p] = ei3[j];
  }
}

// ---------------- small converts ----------------
__global__ __launch_bounds__(256) void k_cvt16(const float* __restrict__ v, f16* __restrict__ o, int n){
  int t = blockIdx.x*256 + threadIdx.x;
  if (t < n) o[t] = (f16)v[t];
}

// ---------------- NNConv pieces ----------------
__global__ __launch_bounds__(256) void k_packPrep(const float* __restrict__ root,
    const float* __restrict__ b2, f16* __restrict__ Bp, int mi, int mo, int S, int NB){
  int t = blockIdx.x*256 + threadIdx.x;
  if (t >= NB*S*512) return;
  int j = t & 7, l = (t >> 3) & 63, cs = t >> 9;
  int s = cs % S, c = cs / S;
  int k_in = s*32 + ((l>>4)<<3) + j;
  int n = c*16 + (l & 15);
  float v = 0.f;
  if (k_in < mi) v = (n < mo) ? root[k_in*mo + n] : b2[k_in*mo + (n - mo)];
  Bp[t] = (f16)v;
}

// prep[n,o] = bias[o] + (x@root)[n,o]; bterm[n,o] = (x@b2)[n,o]
template<int MI, int S, int NB, int MO>
__global__ __launch_bounds__(256) void k_prep_mfma(const f16* __restrict__ A,
    const f16* __restrict__ Bp, const float* __restrict__ bias,
    float* __restrict__ prep, float* __restrict__ bterm){
  int l = threadIdx.x & 63, w = threadIdx.x >> 6;
  int r0 = blockIdx.x*64 + w*16;
  const f16* arow = A + (size_t)(r0 + (l & 15))*MI;
  f16x8 a[S];
  #pragma unroll
  for (int s=0;s<S;s++){
    int koff = s*32 + ((l>>4)<<3);
    if (koff < MI) a[s] = *(const f16x8*)(arow + koff);
    else           a[s] = (f16x8){0,0,0,0,0,0,0,0};
  }
  #pragma unroll
  for (int c=0;c<NB;c++){
    f32x4 acc = (f32x4){0.f,0.f,0.f,0.f};
    #pragma unroll
    for (int s=0;s<S;s++){
      f16x8 b = *(const f16x8*)(Bp + ((size_t)(c*S + s)*64 + l)*8);
      acc = __builtin_amdgcn_mfma_f32_16x16x32_f16(a[s], b, acc, 0, 0, 0);
    }
    int col = c*16 + (l & 15);
    #pragma unroll
    for (int r=0;r<4;r++){
      int row = r0 + ((l>>4)<<2) + r;
      if (col < MO) prep[(size_t)row*MO + col] = acc[r] + bias[col];
      else          bterm[(size_t)row*MO + (col - MO)] = acc[r];
    }
  }
}

__global__ __launch_bounds__(256) void k_w2pack_full(const float* __restrict__ W2,
    f16* __restrict__ Bp, int mi, int mo, int S){
  int t = blockIdx.x*256 + threadIdx.x;
  if (t >= mo*8*S*512) return;
  int j = t & 7, l = (t >> 3) & 63, cs = t >> 9;
  int s = cs % S, q = cs / S;
  int oc = q >> 3;
  int k  = (q & 7)*16 + (l & 15);
  int i  = s*32 + ((l>>4)<<3) + j;
  float v = (i < mi) ? W2[(size_t)k*mi*mo + (size_t)i*mo + oc] : 0.f;
  Bp[t] = (f16)v;
}

// FUSED NNConv v7: 16 nodes/block, WAVE-PRIVATE oc-pair chunks, barrier-free chunk loop.
// Wave w handles ocpairs cp = w, w+4, ... Each: MFMA M[16n][2oc][128k] into its own
// LDS region, in-wave lgkmcnt hand-off, consume edges. Only 3 barriers/super-tile.
template<int MI, int S, int MO>
__global__ __launch_bounds__(256) void k_nnconv_fused7(const f16* __restrict__ xin16,
    const f16* __restrict__ W2p,
    const int* __restrict__ rowptr, const int* __restrict__ rowend,
    const int* __restrict__ srcs, const int* __restrict__ eids,
    const float* __restrict__ ea, const float* __restrict__ W1,
    const float* __restrict__ b1,
    const float* __restrict__ bterm, f16* __restrict__ msg16){
  __shared__ __align__(16) f16   M[4*16*WNSTR];  // 35840 B (per-wave 16*280)
  __shared__ __align__(16) f16   hb[ECAP*OCS];   // 26112 B
  __shared__ __align__(16) float eas[ECAP*8];    //  3072 B
  __shared__ float bt[16*MO];                    // 4096/2048 B
  int t = threadIdx.x, l = t & 63, w = t >> 6;
  int n0 = blockIdx.x*16;
  int estart = rowptr[n0], eend = rowend[n0+15];
  if (estart >= eend) return;                    // block-uniform
  for (int idx = t; idx < 16*MO; idx += 256) bt[idx] = bterm[(size_t)n0*MO + idx];
  const f16* arow = xin16 + (size_t)(n0 + (l&15))*MI;
  f16x8 a[S];
  #pragma unroll
  for (int s=0;s<S;s++){
    int koff = s*32 + ((l>>4)<<3);
    if (koff < MI) a[s] = *(const f16x8*)(arow + koff);
    else           a[s] = (f16x8){0,0,0,0,0,0,0,0};
  }
  f16* Mw = &M[w*16*WNSTR];
  const int NCP = MO/8;                          // ocpairs per wave
  int eslot = l >> 1, ocl = l & 1;               // 32 edge slots x 2 oc
  for (int ebase = estart; ebase < eend; ebase += ECAP){
    int ecnt = eend - ebase; if (ecnt > ECAP) ecnt = ECAP;
    // ---- stage ea rows ----
    for (int idx = t; idx < ecnt*8; idx += 256){
      int e_ = idx >> 3, i = idx & 7;
      eas[idx] = (i < 7) ? ea[(size_t)eids[ebase + e_]*7 + i] : 0.f;
    }
    __syncthreads();
    // ---- fused edge-MLP -> hb ----
    for (int idx = t; idx < ecnt*32; idx += 256){
      int e_ = idx >> 5, p = idx & 31;
      int k0 = p*4;
      const float* xr = &eas[e_*8];
      float4 acc4 = *(const float4*)(b1 + k0);
      #pragma unroll
      for (int i=0;i<7;i++){
        float xv = xr[i];
        float4 wv = *(const float4*)(W1 + i*KH + k0);
        acc4.x = fmaf(xv, wv.x, acc4.x);
        acc4.y = fmaf(xv, wv.y, acc4.y);
        acc4.z = fmaf(xv, wv.z, acc4.z);
        acc4.w = fmaf(xv, wv.w, acc4.w);
      }
      f16x4 hv = { (f16)fmaxf(acc4.x,0.f), (f16)fmaxf(acc4.y,0.f),
                   (f16)fmaxf(acc4.z,0.f), (f16)fmaxf(acc4.w,0.f) };
      *(f16x4*)&hb[e_*OCS + k0] = hv;
    }
    __syncthreads();
    // ---- wave-private chunk loop (no block barriers) ----
    for (int i = 0; i < NCP; i++){
      int cp = w + 4*i;                          // global ocpair
      // stage 1: M[16n][2oc][128k] via MFMA -> wave-private LDS
      #pragma unroll
      for (int tt = 0; tt < 16; tt++){
        int q = (2*cp + (tt>>3))*8 + (tt&7);
        f32x4 acc = (f32x4){0.f,0.f,0.f,0.f};
        #pragma unroll
        for (int s=0;s<S;s++){
          f16x8 b = *(const f16x8*)(W2p + ((size_t)(q*S + s)*64 + l)*8);
          acc = __builtin_amdgcn_mfma_f32_16x16x32_f16(a[s], b, acc, 0, 0, 0);
        }
        int od = (tt>>3)*OCS;
        int kpos = (tt&7)*16 + (l & 15);
        f16* mp = &Mw[od + kpos];
        #pragma unroll
        for (int r=0;r<4;r++)
          mp[(size_t)(((l>>4)<<2) + r)*WNSTR] = (f16)acc[r];
      }
      __asm__ volatile("s_waitcnt lgkmcnt(0)" ::: "memory");  // in-wave hand-off
      // stage 2: consume edges for this ocpair
      #pragma unroll
      for (int r2 = 0; r2 < ECAP/32; r2++){
        int ee = r2*32 + eslot;
        if (ee < ecnt){
          int e = ebase + ee;
          int ln = srcs[e] - n0;
          float acc = bt[ln*MO + 2*cp + ocl];
          const f16* mrow = &Mw[(size_t)ln*WNSTR + ocl*OCS];
          const f16* hrow = &hb[ee*OCS];
          #pragma unroll 4
          for (int kk=0; kk<16; kk++){
            f16x8 h8 = *(const f16x8*)(hrow + kk*8);
            f16x8 m8 = *(const f16x8*)(mrow + kk*8);
            #pragma unroll
            for (int j=0;j<4;j++){
              acc = dot2acc((f16x2){h8[2*j],h8[2*j+1]}, (f16x2){m8[2*j],m8[2*j+1]}, acc);
            }
          }
          msg16[(size_t)e*MO + 2*cp + ocl] = (f16)acc;
        }
      }
      __asm__ volatile("s_waitcnt lgkmcnt(0)" ::: "memory");  // reads done before rewrite
    }
    __syncthreads();  // protect eas/hb before next super-tile
  }
}

// dst-CSR gather of conv messages, 4-wide batched loads:
// out16[n,o] = elu(prep[n,o] + sum msg[dpos[p], o])
template<int MO>
__global__ __launch_bounds__(256) void k_msg_gather(const int* __restrict__ dptr,
    const int* __restrict__ dend, const int* __restrict__ dpos,
    const f16* __restrict__ msg, const float* __restrict__ prep,
    f16* __restrict__ out16){
  int t = threadIdx.x, l = t & 63, w = t >> 6;
  int n, o;
  if (MO == 64){ n = blockIdx.x*4 + w; o = l; }
  else         { n = blockIdx.x*8 + w*2 + (l>>5); o = l & 31; }
  int st = dptr[n], en = dend[n];
  float acc = prep[(size_t)n*MO + o];
  int p = st;
  for (; p + 4 <= en; p += 4){
    int q0 = dpos[p], q1 = dpos[p+1], q2 = dpos[p+2], q3 = dpos[p+3];
    float v0 = (float)msg[(size_t)q0*MO + o];
    float v1 = (float)msg[(size_t)q1*MO + o];
    float v2 = (float)msg[(size_t)q2*MO + o];
    float v3 = (float)msg[(size_t)q3*MO + o];
    acc += (v0 + v1) + (v2 + v3);
  }
  for (; p < en; p++) acc += (float)msg[(size_t)dpos[p]*MO + o];
  out16[(size_t)n*MO + o] = (f16)elu1(acc);
}

// ---------------- pooling via cluster-CSR, dual-level, 4-wide ----------------
__global__ __launch_bounds__(256) void k_pool_gather_dual(const int* __restrict__ aptr,
    const int* __restrict__ aend, const int* __restrict__ ans2, const int* __restrict__ ans3,
    const f16* __restrict__ h, const float* __restrict__ iso2, const float* __restrict__ iso3,
    f16* __restrict__ h16){
  int l = threadIdx.x & 63, w = threadIdx.x >> 6;
  int cg = blockIdx.x*4 + w;               // [0, 2*NC2)
  int lvl = cg >= NC2;
  int c = cg - lvl*NC2;
  const int* ans = lvl ? ans3 : ans2;
  const float* iso = lvl ? iso3 : iso2;
  int st = aptr[cg], en = aend[cg];
  float acc = 0.f;
  int e = st;
  for (; e + 4 <= en; e += 4){
    int n0 = ans[e], n1 = ans[e+1], n2 = ans[e+2], n3 = ans[e+3];
    float v0 = (float)h[(size_t)n0*64 + l];
    float v1 = (float)h[(size_t)n1*64 + l];
    float v2 = (float)h[(size_t)n2*64 + l];
    float v3 = (float)h[(size_t)n3*64 + l];
    acc += (v0 + v1) + (v2 + v3);
  }
  for (; e < en; e++) acc += (float)h[(size_t)ans[e]*64 + l];
  int cnt = en - st;
  float val = (cnt > 0) ? acc / (float)cnt : 0.f;
  h16[(size_t)cg*128 + l] = (f16)val;
  h16[(size_t)cg*128 + 64 + l] = (f16)iso[(size_t)c*64 + l];
}

// ---------------- GraphConv (dual-level) ----------------
#define BP_O4 0
#define BP_O5 16384
#define BP_O6 24576
#define BP_O7 40960
__global__ __launch_bounds__(256) void k_packB_all(
    const float* __restrict__ W4r, const float* __restrict__ W4o,
    const float* __restrict__ W5r, const float* __restrict__ W5o,
    const float* __restrict__ W6r, const float* __restrict__ W6o,
    const float* __restrict__ W7r, const float* __restrict__ W7o,
    f16* __restrict__ Bp){
  int t = blockIdx.x*256 + threadIdx.x;
  const float *Wrel, *Wroot; int S, base;
  if      (t < BP_O5){ Wrel=W4r; Wroot=W4o; S=4; base=BP_O4; }
  else if (t < BP_O6){ Wrel=W5r; Wroot=W5o; S=2; base=BP_O5; }
  else if (t < BP_O7){ Wrel=W6r; Wroot=W6o; S=4; base=BP_O6; }
  else if (t < 49152){ Wrel=W7r; Wroot=W7o; S=2; base=BP_O7; }
  else return;
  int u = t - base;
  int j = u & 7, l = (u >> 3) & 63, cs = u >> 9;
  int s = cs % S, c = cs / S;
  int k = s*32 + ((l>>4)<<3) + j;
  int n = (c<<4) + (l & 15);
  float v = (n < 64) ? Wrel[k*64 + n] : Wroot[k*64 + (n - 64)];
  Bp[t] = (f16)v;
}

template<int S>
__global__ __launch_bounds__(256) void k_gc_mfma_dual(const f16* __restrict__ Abase,
    const f16* __restrict__ Bp, int bpo2, int bpo3,
    const float* __restrict__ bias2, const float* __restrict__ bias3,
    f16* __restrict__ y16, f16* __restrict__ rbuf16){
  const int half = NC2/64;
  int lvl = blockIdx.x >= half;
  int bloc = blockIdx.x - lvl*half;
  const f16* A = Abase + (size_t)lvl*NC2*(S*32);
  const f16* B = Bp + (lvl ? bpo3 : bpo2);
  const float* bias = lvl ? bias3 : bias2;
  f16* y  = y16 + (size_t)lvl*NC2*64;
  f16* rb = rbuf16 + (size_t)lvl*NC2*64;
  int l = threadIdx.x & 63, w = threadIdx.x >> 6;
  int r0 = bloc*64 + w*16;
  const f16* arow = A + (size_t)(r0 + (l & 15))*(S*32);
  f16x8 a[S];
  #pragma unroll
  for (int s=0;s<S;s++) a[s] = *(const f16x8*)(arow + s*32 + ((l>>4)<<3));
  f32x4 acc[8];
  #pragma unroll
  for (int c=0;c<8;c++) acc[c] = (f32x4){0.f,0.f,0.f,0.f};
  #pragma unroll
  for (int c=0;c<8;c++){
    #pragma unroll
    for (int s=0;s<S;s++){
      f16x8 b = *(const f16x8*)(B + ((size_t)(c*S + s)*64 + l)*8);
      acc[c] = __builtin_amdgcn_mfma_f32_16x16x32_f16(a[s], b, acc[c], 0, 0, 0);
    }
  }
  #pragma unroll
  for (int c=0;c<8;c++){
    int col = c*16 + (l & 15);
    #pragma unroll
    for (int r=0;r<4;r++){
      int row = r0 + ((l>>4)<<2) + r;
      if (col < 64) y[(size_t)row*64 + col] = (f16)acc[c][r];
      else          rb[(size_t)row*64 + (col-64)] = (f16)(acc[c][r] + bias[col-64]);
    }
  }
}

__global__ __launch_bounds__(256) void k_gc_gather_dual(const int* __restrict__ dptrD,
    const int* __restrict__ dcurD, const int* __restrict__ dsrc2, const int* __restrict__ dsrc3,
    const f16* __restrict__ y16, const f16* __restrict__ rbuf16,
    f16* __restrict__ obase){
  int l = threadIdx.x & 63, w = threadIdx.x >> 6;
  int ng = blockIdx.x*4 + w;               // [0, 2*NC2)
  int lvl = ng >= NC2;
  int n = ng - lvl*NC2;
  const int* dsrc = lvl ? dsrc3 : dsrc2;
  const f16* y  = y16 + (size_t)lvl*NC2*64;
  const f16* rb = rbuf16 + (size_t)lvl*NC2*64;
  f16* o = obase + (size_t)lvl*NC2*64;
  int st = dptrD[ng], en = dcurD[ng];
  float acc = (float)rb[(size_t)n*64 + l];
  int e = st;
  for (; e + 4 <= en; e += 4){
    int s0 = dsrc[e], s1 = dsrc[e+1], s2 = dsrc[e+2], s3 = dsrc[e+3];
    float v0 = (float)y[(size_t)s0*64 + l];
    float v1 = (float)y[(size_t)s1*64 + l];
    float v2 = (float)y[(size_t)s2*64 + l];
    float v3 = (float)y[(size_t)s3*64 + l];
    acc += (v0 + v1) + (v2 + v3);
  }
  for (; e < en; e++) acc += (float)y[(size_t)dsrc[e]*64 + l];
  o[(size_t)n*64 + l] = (f16)elu1(acc);
}

// ---------------- 3-way sorted-segment batch sum ----------------
__device__ __forceinline__ int lowerb(const int* __restrict__ a, int n, int key){
  int lo = 0, hi = n;
  while (lo < hi){ int m = (lo + hi) >> 1; if (a[m] < key) lo = m + 1; else hi = m; }
  return lo;
}

__global__ __launch_bounds__(256) void k_batchsum3(const int* __restrict__ b1,
    const int* __restrict__ b2, const int* __restrict__ b3,
    const f16* __restrict__ s1, const f16* __restrict__ s2, const f16* __restrict__ s3,
    float* __restrict__ x123){
  __shared__ float red[4][64];
  int seg = blockIdx.x >> 8, b = blockIdx.x & 255;
  const int* batch = (seg==0) ? b1 : ((seg==1) ? b2 : b3);
  const f16* src   = (seg==0) ? s1 : ((seg==1) ? s2 : s3);
  int nn = (seg==0) ? NN : NC2;
  int lo = lowerb(batch, nn, b);
  int hi = lowerb(batch, nn, b+1);
  int col = threadIdx.x & 63, wq = threadIdx.x >> 6;
  float acc = 0.f;
  for (int n = lo + wq; n < hi; n += 4) acc += (float)src[(size_t)n*64 + col];
  red[wq][col] = acc;
  __syncthreads();
  if (threadIdx.x < 64){
    float s = red[0][threadIdx.x] + red[1][threadIdx.x] + red[2][threadIdx.x] + red[3][threadIdx.x];
    x123[b*192 + seg*64 + threadIdx.x] = s;
  }
}

// ---------------- FC head ----------------
__global__ __launch_bounds__(256) void k_fc1(const float* __restrict__ x123,
    const float* __restrict__ W, const float* __restrict__ b, float* __restrict__ t1){
  int t = blockIdx.x*256 + threadIdx.x;
  if (t >= NBATCH*64) return;
  int bb = t >> 6, o = t & 63;
  const float* xr = x123 + bb*192;
  float acc = b[o];
  for (int j=0;j<192;j++) acc = fmaf(xr[j], W[j*64+o] + W[(192+j)*64+o], acc);
  t1[t] = elu1(acc);
}

__global__ __launch_bounds__(256) void k_fc2(const float* __restrict__ t1,
    const float* __restrict__ W, const float* __restrict__ b, float* __restrict__ t2){
  int t = blockIdx.x*256 + threadIdx.x;
  if (t >= NBATCH*32) return;
  int bb = t >> 5, o = t & 31;
  float acc = b[o];
  for (int j=0;j<64;j++) acc = fmaf(t1[bb*64+j], W[j*32+o], acc);
  t2[t] = elu1(acc);
}

__global__ __launch_bounds__(256) void k_fc3(const float* __restrict__ t2,
    const float* __restrict__ W, const float* __restrict__ b, float* __restrict__ out){
  int t = blockIdx.x*256 + threadIdx.x;
  if (t >= NBATCH) return;
  float acc = b[0];
  for (int j=0;j<32;j++) acc = fmaf(t2[t*32+j], W[j], acc);
  out[t] = acc;
}

static inline int cdiv(long long a, int b){ return (int)((a + b - 1) / b); }

extern "C" void kernel_launch(void* const* d_in, const int* in_sizes, int n_in,
                              void* d_out, int out_size, void* d_ws, size_t ws_size,
                              hipStream_t stream) {
  const float* x0    = (const float*)d_in[0];
  const int*   ei    = (const int*)d_in[1];
  const float* ea    = (const float*)d_in[2];
  const int*   batch = (const int*)d_in[3];
  const int*   a2n   = (const int*)d_in[4];
  const int*   a2c   = (const int*)d_in[5];
  const float* iso2  = (const float*)d_in[6];
  const int*   ei2   = (const int*)d_in[7];
  const int*   b2arr = (const int*)d_in[8];
  const int*   a3n   = (const int*)d_in[9];
  const int*   a3c   = (const int*)d_in[10];
  const float* iso3  = (const float*)d_in[11];
  const int*   ei3   = (const int*)d_in[12];
  const int*   b3arr = (const int*)d_in[13];
  const float* nnp[3][6];
  for (int c=0;c<3;c++) for (int p=0;p<6;p++) nnp[c][p] = (const float*)d_in[14 + 6*c + p];
  const float* c4W[3]; const float* c5W[3]; const float* c6W[3]; const float* c7W[3];
  for (int p=0;p<3;p++){ c4W[p]=(const float*)d_in[32+p]; c5W[p]=(const float*)d_in[35+p];
                         c6W[p]=(const float*)d_in[38+p]; c7W[p]=(const float*)d_in[41+p]; }
  const float* fc1W=(const float*)d_in[44]; const float* fc1b=(const float*)d_in[45];
  const float* fc2W=(const float*)d_in[46]; const float* fc2b=(const float*)d_in[47];
  const float* fc3W=(const float*)d_in[48]; const float* fc3b=(const float*)d_in[49];
  float* outp = (float*)d_out;

  // ---- workspace carve ----
  char* ws = (char*)d_ws; size_t off = 0;
  auto alloc = [&](size_t bytes)->void*{ void* p = ws + off; off += (bytes + 255) & ~(size_t)255; return p; };
  const size_t SZ_R0 = (size_t)92*1024*1024;
  char* r0 = (char*)alloc(SZ_R0);
  // phase-1 view (NNConv): W2p 1MB | prepB 64KB | bterm 4MB | prep 4MB | msg 8MB
  f16*   W2p   = (f16*)r0;
  f16*   prepB = (f16*)(r0 + 2*1024*1024);
  float* bterm = (float*)(r0 + 2*1024*1024 + 64*1024);
  float* prep  = (float*)(r0 + 2*1024*1024 + 64*1024 + (size_t)NN*64*4);
  f16*   msg16 = (f16*)  (r0 + 2*1024*1024 + 64*1024 + (size_t)NN*64*8);
  // phase-2 view (written only after all NNConvs + gathers complete)
  size_t o2 = 0;
  auto a2 = [&](size_t bytes)->char*{ char* p = r0 + o2; o2 += (bytes + 255) & ~(size_t)255; return p; };
  f16*   h16   = (f16*)  a2((size_t)2*NC2*128*2);  // 32 MB
  f16*   y16   = (f16*)  a2((size_t)2*NC2*64*2);   // 16 MB
  f16*   rbuf16= (f16*)  a2((size_t)2*NC2*64*2);   // 16 MB
  f16*   g16   = (f16*)  a2((size_t)2*NC2*64*2);   // 16 MB
  f16*   BpGc  = (f16*)  a2((size_t)49152*2);      // 96 KB
  int*   ldegA = (int*)  a2((size_t)4*NC2*4);
  int*   ldegD = ldegA + 2*NC2;
  int*   ptrA  = (int*)  a2((size_t)2*NC2*4);
  int*   curA  = (int*)  a2((size_t)2*NC2*4);
  int*   ptrD  = (int*)  a2((size_t)2*NC2*4);
  int*   curD  = (int*)  a2((size_t)2*NC2*4);
  int*   ans2  = (int*)  a2((size_t)A2N*4);
  int*   ans3  = (int*)  a2((size_t)A3N*4);
  int*   dsrc2 = (int*)  a2((size_t)ELV*4);
  int*   dsrc3 = (int*)  a2((size_t)ELV*4);
  f16*   fin2  = h16;                       // layer-2 outputs reuse h16 region
  f16*   fin3  = h16 + (size_t)NC2*64;
  // persistent
  f16*   x016  = (f16*)  alloc((size_t)NN*16*2);
  f16*   hA16  = (f16*)  alloc((size_t)NN*32*2);
  f16*   hB16  = (f16*)  alloc((size_t)NN*64*2);
  f16*   hC16  = (f16*)  alloc((size_t)NN*64*2);
  int*   deg1  = (int*)  alloc((size_t)2*NN*4);
  int*   ptr1  = (int*)  alloc((size_t)2*NN*4);
  int*   cur1  = (int*)  alloc((size_t)2*NN*4);
  int*   eids  = (int*)  alloc((size_t)E1N*4);
  int*   srcs  = (int*)  alloc((size_t)E1N*4);
  int*   dpos  = (int*)  alloc((size_t)E1N*4);
  int*   parts = (int*)  alloc((size_t)512*4);
  float* x123  = (float*)alloc((size_t)NBATCH*192*4);
  float* t1    = (float*)alloc((size_t)NBATCH*64*4);
  float* t2    = (float*)alloc((size_t)NBATCH*32*4);
  (void)ws_size; (void)n_in; (void)in_sizes; (void)out_size;

  auto scan = [&](const int* dg, int totalN, int segs, int* ptr, int* cur){
    int nb = totalN/256/segs;
    k_scan1<<<totalN/256,256,0,stream>>>(dg, ptr, parts);
    k_scan2seg<<<segs,256,0,stream>>>(parts, nb);
    k_scan3<<<totalN/256,256,0,stream>>>(parts, ptr, cur);
  };

  // ---- level-1 CSR: src-sorted edges + dst-CSR of positions (one pass) ----
  hipMemsetAsync(deg1, 0, (size_t)2*NN*4, stream);
  k_count_edge_dual<<<cdiv(E1N,256),256,0,stream>>>(ei, deg1);
  scan(deg1, 2*NN, 2, ptr1, cur1);
  k_fill_edge_dual<<<cdiv(E1N,256),256,0,stream>>>(ei, cur1, eids, srcs, dpos);
  k_cvt16<<<cdiv((long long)NN*16,256),256,0,stream>>>(x0, x016, NN*16);

  // ---- NNConv x3 (fused v7 + 4-wide msg gather) ----
  auto run_nnconv = [&](const f16* xin16, int mi, int mo,
                        const float* const* P, f16* out16){
    const float* W1=P[0]; const float* b1=P[1]; const float* W2=P[2];
    const float* b2=P[3]; const float* root=P[4]; const float* bias=P[5];
    const int S = (mi > 32) ? 2 : 1;
    const int NB = (2*mo)/16;
    k_packPrep<<<cdiv((long long)NB*S*512,256),256,0,stream>>>(root, b2, prepB, mi, mo, S, NB);
    if (mi==16)      k_prep_mfma<16,1,4,32><<<NN/64,256,0,stream>>>(xin16, prepB, bias, prep, bterm);
    else if (mi==32) k_prep_mfma<32,1,8,64><<<NN/64,256,0,stream>>>(xin16, prepB, bias, prep, bterm);
    else             k_prep_mfma<64,2,8,64><<<NN/64,256,0,stream>>>(xin16, prepB, bias, prep, bterm);
    k_w2pack_full<<<cdiv((long long)mo*8*S*512,256),256,0,stream>>>(W2, W2p, mi, mo, S);
    if (mi==16)      k_nnconv_fused7<16,1,32><<<NN/16,256,0,stream>>>(xin16, W2p, ptr1, cur1, srcs, eids, ea, W1, b1, bterm, msg16);
    else if (mi==32) k_nnconv_fused7<32,1,64><<<NN/16,256,0,stream>>>(xin16, W2p, ptr1, cur1, srcs, eids, ea, W1, b1, bterm, msg16);
    else             k_nnconv_fused7<64,2,64><<<NN/16,256,0,stream>>>(xin16, W2p, ptr1, cur1, srcs, eids, ea, W1, b1, bterm, msg16);
    if (mo==32) k_msg_gather<32><<<NN/8,256,0,stream>>>(ptr1+NN, cur1+NN, dpos, msg16, prep, out16);
    else        k_msg_gather<64><<<NN/4,256,0,stream>>>(ptr1+NN, cur1+NN, dpos, msg16, prep, out16);
  };
  run_nnconv(x016, 16, 32, nnp[0], hA16);
  run_nnconv(hA16, 32, 64, nnp[1], hB16);
  run_nnconv(hB16, 64, 64, nnp[2], hC16);

  // ---- level-2/3 CSR builds (dual) ----
  hipMemsetAsync(ldegA, 0, (size_t)4*NC2*4, stream);
  k_count_assign_dual<<<cdiv((long long)(A2N+A3N),256),256,0,stream>>>(a2c, a3c, ldegA);
  scan(ldegA, 2*NC2, 2, ptrA, curA);
  k_fill_assign_dual<<<cdiv((long long)(A2N+A3N),256),256,0,stream>>>(a2n, a2c, a3n, a3c, curA, ans2, ans3);
  k_count_dst_dual<<<cdiv((long long)2*ELV,256),256,0,stream>>>(ei2, ei3, ldegD);
  scan(ldegD, 2*NC2, 2, ptrD, curD);
  k_fill_dst_dual<<<cdiv((long long)2*ELV,256),256,0,stream>>>(ei2, ei3, curD, dsrc2, dsrc3);

  // ---- levels compute (dual launches) ----
  k_pool_gather_dual<<<2*NC2/4,256,0,stream>>>(ptrA, curA, ans2, ans3, hC16, iso2, iso3, h16);
  k_packB_all<<<cdiv(49152,256),256,0,stream>>>(c4W[0], c4W[1], c5W[0], c5W[1],
                                                c6W[0], c6W[1], c7W[0], c7W[1], BpGc);
  k_gc_mfma_dual<4><<<2*NC2/64,256,0,stream>>>(h16, BpGc, BP_O4, BP_O6, c4W[2], c6W[2], y16, rbuf16);
  k_gc_gather_dual<<<2*NC2/4,256,0,stream>>>(ptrD, curD, dsrc2, dsrc3, y16, rbuf16, g16);
  k_gc_mfma_dual<2><<<2*NC2/64,256,0,stream>>>(g16, BpGc, BP_O5, BP_O7, c5W[2], c7W[2], y16, rbuf16);
  k_gc_gather_dual<<<2*NC2/4,256,0,stream>>>(ptrD, curD, dsrc2, dsrc3, y16, rbuf16, fin2);

  // ---- batch sums (3 segments in one launch) + FC head ----
  k_batchsum3<<<3*NBATCH,256,0,stream>>>(batch, b2arr, b3arr, hC16, fin2, fin3, x123);
  k_fc1<<<cdiv((long long)NBATCH*64,256),256,0,stream>>>(x123, fc1W, fc1b, t1);
  k_fc2<<<cdiv((long long)NBATCH*32,256),256,0,stream>>>(t1, fc2W, fc2b, t2);
  k_fc3<<<cdiv(NBATCH,256),256,0,stream>>>(t2, fc3W, fc3b, outp);
}